// Round 2
// baseline (1687.532 us; speedup 1.0000x reference)
//
#include <hip/hip_runtime.h>
#include <hip/hip_bf16.h>

typedef __hip_bfloat16 bf16;
typedef unsigned short ushort_t;
typedef __attribute__((ext_vector_type(8))) short short8v;
typedef __attribute__((ext_vector_type(4))) float floatx4;

#define NEG_SLOPE 0.15f

__device__ __forceinline__ float us2f(unsigned short u) {
    unsigned int x = ((unsigned int)u) << 16;
    float f;
    __builtin_memcpy(&f, &x, 4);
    return f;
}
__device__ __forceinline__ unsigned short f2us(float v) {
    bf16 h = __float2bfloat16(v);
    unsigned short u;
    __builtin_memcpy(&u, &h, 2);
    return u;
}

// direct global->LDS async copy, 16B per lane (linear LDS dest; swizzle is
// applied on the SOURCE address + matching XOR on the ds_read side).
#define GLOAD_LDS16(gp, lp)                                                  \
    __builtin_amdgcn_global_load_lds(                                        \
        (const __attribute__((address_space(1))) unsigned int*)(gp),         \
        (__attribute__((address_space(3))) unsigned int*)(lp), 16, 0, 0)

// ---------------------------------------------------------- grid-wide barrier
// Requires cooperative launch (co-resident grid). One counter per sync point,
// zeroed by hipMemsetAsync before launch. threadfence = agent-scope fence
// (L1 inv + waitcnt) so cross-XCD writes are visible after the barrier.
__device__ __forceinline__ void gsync(int* ctr, int nbk) {
    __threadfence();
    __syncthreads();
    if (threadIdx.x == 0) {
        __hip_atomic_fetch_add(ctr, 1, __ATOMIC_ACQ_REL, __HIP_MEMORY_SCOPE_AGENT);
        while (__hip_atomic_load(ctr, __ATOMIC_ACQUIRE, __HIP_MEMORY_SCOPE_AGENT) < nbk)
            __builtin_amdgcn_s_sleep(2);
    }
    __syncthreads();
    __threadfence();
}

// ---------------------------------------------------------- per-block dtype flag
__device__ __forceinline__ int block_flag(const unsigned int* __restrict__ xw) {
    __shared__ int cnt;
    if (threadIdx.x == 0) cnt = 0;
    __syncthreads();
    if (threadIdx.x < 256) {
        unsigned int w = xw[threadIdx.x];
        unsigned int e = (w >> 7) & 0xFF;
        if ((w & 0xFFFF) == 0 || (e >= 100 && e <= 140)) atomicAdd(&cnt, 1);
    }
    __syncthreads();
    return cnt >= 150;
}

// ---------------------------------------------------------------- prep tasks
// K==0 -> fp32 convert; K>0 -> transpose W[K x Nn] -> bf16 Wt[Nn x K];
// K==-2 -> convert x to bf16 (strided loop over 512 virtual blocks).
struct PrepDesc {
    const void* src[13];
    void* dst[13];
    int n[13];
    int K[13], Nn[13];
};

__device__ __forceinline__ void prep_task(const PrepDesc& d, int t, int b, int tid,
                                          int f) {
    int Kt = d.K[t];
    int nt = d.n[t];
    if (Kt == -2) {
        ushort_t* out = (ushort_t*)d.dst[t];
        const void* in = d.src[t];
        const int stride = 512 * 256;
        for (int i = b * 256 + tid; i < nt; i += stride)
            out[i] = f ? ((const unsigned short*)in)[i] : f2us(((const float*)in)[i]);
        return;
    }
    int i = b * 256 + tid;
    if (i >= nt) return;
    if (Kt == 0) {
        ((float*)d.dst[t])[i] = f ? us2f(((const unsigned short*)d.src[t])[i])
                                  : ((const float*)d.src[t])[i];
    } else {
        int K = Kt, Nn = d.Nn[t];
        int n = i / K, k = i - n * K;
        size_t si = (size_t)k * Nn + n;
        ((ushort_t*)d.dst[t])[i] = f ? ((const unsigned short*)d.src[t])[si]
                                     : f2us(((const float*)d.src[t])[si]);
    }
}

__global__ void prep_small_kernel(PrepDesc d, const void* __restrict__ xsrc) {
    int f = block_flag((const unsigned int*)xsrc);
    prep_task(d, blockIdx.y, blockIdx.x, threadIdx.x, f);
}

// ---------------------------------------------------------------- CSR build (fallback)
__global__ void count_deg_kernel(const int* __restrict__ dst, int* __restrict__ deg,
                                 int E, int N) {
    int i = blockIdx.x * blockDim.x + threadIdx.x;
    if (i < E) {
        int d = dst[i];
        d = d < 0 ? 0 : (d >= N ? N - 1 : d);
        atomicAdd(&deg[d], 1);
    }
}

__global__ void scan_merged_kernel(const int* __restrict__ deg, int* __restrict__ offsets,
                                   int* __restrict__ cursor, float* __restrict__ dis,
                                   int* __restrict__ bsumf, int N) {
    __shared__ int sh[1024];
    __shared__ int base_s;
    int tid = threadIdx.x;
    int b = blockIdx.x;
    int i = b * 1024 + tid;
    int v = (i < N) ? (deg[i] + 1) : 0;
    sh[tid] = v;
    __syncthreads();
    for (int off = 1; off < 1024; off <<= 1) {
        int t = (tid >= off) ? sh[tid - off] : 0;
        __syncthreads();
        sh[tid] += t;
        __syncthreads();
    }
    if (tid == 0) {
        __hip_atomic_store(&bsumf[b], sh[1023] + 1, __ATOMIC_RELEASE,
                           __HIP_MEMORY_SCOPE_AGENT);
        int a = 0;
        for (int pb = 0; pb < b; ++pb) {
            int val;
            do {
                val = __hip_atomic_load(&bsumf[pb], __ATOMIC_ACQUIRE,
                                        __HIP_MEMORY_SCOPE_AGENT);
            } while (val == 0);
            a += val - 1;
        }
        base_s = a;
    }
    __syncthreads();
    if (i < N) {
        int base = base_s;
        int d = deg[i] + 1;
        int inc = sh[tid];
        int excl = base + inc - d;
        offsets[i] = excl;
        cursor[i] = excl;
        dis[i] = rsqrtf((float)d);
        if (i == N - 1) offsets[N] = base + inc;
    }
}

__global__ void fill_csr_kernel(const int* __restrict__ src, const int* __restrict__ dst,
                                const float* __restrict__ dis, int* __restrict__ cursor,
                                int2* __restrict__ edges, int E, int N, int Etot) {
    int i = blockIdx.x * blockDim.x + threadIdx.x;
    int s, d;
    if (i < E) { s = src[i]; d = dst[i]; }
    else if (i < Etot) { s = d = i - E; }
    else return;
    s = s < 0 ? 0 : (s >= N ? N - 1 : s);
    d = d < 0 ? 0 : (d >= N ? N - 1 : d);
    int pos = atomicAdd(&cursor[d], 1);
    if (pos >= 0 && pos < Etot) edges[pos] = make_int2(s, __float_as_int(dis[s]));
}

// ---------------------------------------------------------------- aggregation
template <int VEC> struct LdT;
template <> struct LdT<2> { typedef unsigned int T; };
template <> struct LdT<4> { typedef uint2 T; };

template <int VEC>
__device__ __forceinline__ void addv(typename LdT<VEC>::T u, float w, float* acc);
template <>
__device__ __forceinline__ void addv<2>(unsigned int u, float w, float* acc) {
    acc[0] += w * us2f((unsigned short)(u & 0xFFFF));
    acc[1] += w * us2f((unsigned short)(u >> 16));
}
template <>
__device__ __forceinline__ void addv<4>(uint2 u, float w, float* acc) {
    acc[0] += w * us2f((unsigned short)(u.x & 0xFFFF));
    acc[1] += w * us2f((unsigned short)(u.x >> 16));
    acc[2] += w * us2f((unsigned short)(u.y & 0xFFFF));
    acc[3] += w * us2f((unsigned short)(u.y >> 16));
}

template <int VEC>
__device__ __forceinline__ void agg_core(
    const ushort_t* __restrict__ Hin, const int* __restrict__ offsets,
    const int2* __restrict__ edges, const float* __restrict__ dis,
    int node, int lane, int N, int Etot,
    const float* __restrict__ bias, int do_lrelu, float* outv) {
    typedef typename LdT<VEC>::T LT;
    const int F = VEC * 64;
    int beg = offsets[node], end = offsets[node + 1];
    beg = beg < 0 ? 0 : (beg > Etot ? Etot : beg);
    end = end < beg ? beg : (end > Etot ? Etot : end);

    float acc[VEC];
#pragma unroll
    for (int v = 0; v < VEC; ++v) acc[v] = 0.f;

    int fo = lane * VEC;
    int e = beg;
    for (; e + 8 <= end; e += 8) {
        int2 r[8];
#pragma unroll
        for (int j = 0; j < 8; ++j) r[j] = edges[e + j];
        LT u[8];
#pragma unroll
        for (int j = 0; j < 8; ++j) {
            int s = r[j].x;
            s = s < 0 ? 0 : (s >= N ? N - 1 : s);
            u[j] = *(const LT*)(Hin + (size_t)s * F + fo);
        }
#pragma unroll
        for (int j = 0; j < 8; ++j) addv<VEC>(u[j], __int_as_float(r[j].y), acc);
    }
    if (e + 4 <= end) {
        int2 r[4];
#pragma unroll
        for (int j = 0; j < 4; ++j) r[j] = edges[e + j];
        LT u[4];
#pragma unroll
        for (int j = 0; j < 4; ++j) {
            int s = r[j].x;
            s = s < 0 ? 0 : (s >= N ? N - 1 : s);
            u[j] = *(const LT*)(Hin + (size_t)s * F + fo);
        }
#pragma unroll
        for (int j = 0; j < 4; ++j) addv<VEC>(u[j], __int_as_float(r[j].y), acc);
        e += 4;
    }
    for (; e < end; ++e) {
        int2 r = edges[e];
        int s = r.x;
        s = s < 0 ? 0 : (s >= N ? N - 1 : s);
        LT u = *(const LT*)(Hin + (size_t)s * F + fo);
        addv<VEC>(u, __int_as_float(r.y), acc);
    }

    float dn = dis[node];
#pragma unroll
    for (int v = 0; v < VEC; ++v) {
        float a = acc[v] * dn;
        if (bias) a += bias[fo + v];
        if (do_lrelu) a = (a > 0.f) ? a : a * NEG_SLOPE;
        outv[v] = a;
    }
}

template <int VEC>
__device__ __forceinline__ void agg_store(ushort_t* OutB, int node, int lane,
                                          const float* outv) {
    size_t base = (size_t)node * (VEC * 64) + lane * VEC;
    if (VEC == 2) {
        unsigned int w = ((unsigned int)f2us(outv[1]) << 16) | f2us(outv[0]);
        *(unsigned int*)(OutB + base) = w;
    } else {
        uint2 w;
        w.x = ((unsigned int)f2us(outv[1]) << 16) | f2us(outv[0]);
        w.y = ((unsigned int)f2us(outv[3]) << 16) | f2us(outv[2]);
        *(uint2*)(OutB + base) = w;
    }
}

template <int VEC>
__global__ __launch_bounds__(256) void agg_kernel(
    const ushort_t* __restrict__ Hin, ushort_t* __restrict__ OutB,
    const int* __restrict__ offsets, const int2* __restrict__ edges,
    const float* __restrict__ dis, int N, int Etot,
    const float* __restrict__ bias, int do_lrelu) {
    int lane = threadIdx.x & 63;
    int node = blockIdx.x * 4 + (threadIdx.x >> 6);
    if (node >= N) return;
    float outv[VEC];
    agg_core<VEC>(Hin, offsets, edges, dis, node, lane, N, Etot, bias, do_lrelu, outv);
    agg_store<VEC>(OutB, node, lane, outv);
}

// head MLP on one node's wave: h[2] per lane (feature lane*2, lane*2+1)
__device__ __forceinline__ void head_mlp(
    const float* h, int lane, int node, int flag,
    const float* __restrict__ Wp, const float* __restrict__ bp,
    const float* __restrict__ Wf1, const float* __restrict__ bf1v,
    const float* __restrict__ Wf2, const float* __restrict__ bf2v,
    void* __restrict__ out) {
    int fo = lane * 2;
    float p[16];
#pragma unroll
    for (int j = 0; j < 16; ++j)
        p[j] = h[0] * Wp[fo * 16 + j] + h[1] * Wp[(fo + 1) * 16 + j];
#pragma unroll
    for (int m = 1; m < 64; m <<= 1) {
#pragma unroll
        for (int j = 0; j < 16; ++j) p[j] += __shfl_xor(p[j], m, 64);
    }
    float a0 = 0.f, a1 = 0.f;
    if (lane < 32) {
        float s = bf1v[lane];
#pragma unroll
        for (int k = 0; k < 16; ++k) s += (p[k] + bp[k]) * Wf1[k * 32 + lane];
        s = (s > 0.f) ? s : s * NEG_SLOPE;
        a0 = s * Wf2[lane * 2 + 0];
        a1 = s * Wf2[lane * 2 + 1];
    }
#pragma unroll
    for (int m = 1; m < 64; m <<= 1) {
        a0 += __shfl_xor(a0, m, 64);
        a1 += __shfl_xor(a1, m, 64);
    }
    if (lane == 0) {
        float o0 = a0 + bf2v[0];
        float o1 = a1 + bf2v[1];
        if (flag) {
            unsigned int w = ((unsigned int)f2us(o1) << 16) | f2us(o0);
            *(unsigned int*)((ushort_t*)out + (size_t)node * 2) = w;
        } else {
            *(float2*)((float*)out + (size_t)node * 2) = make_float2(o0, o1);
        }
    }
}

__global__ __launch_bounds__(256) void agg_head_kernel(
    const ushort_t* __restrict__ Hin,
    const int* __restrict__ offsets, const int2* __restrict__ edges,
    const float* __restrict__ dis, int N, int Etot,
    const float* __restrict__ b3,
    const float* __restrict__ Wp, const float* __restrict__ bp,
    const float* __restrict__ Wf1, const float* __restrict__ bf1v,
    const float* __restrict__ Wf2, const float* __restrict__ bf2v,
    void* __restrict__ out, const void* __restrict__ xsrc) {
    int flag = block_flag((const unsigned int*)xsrc);
    int lane = threadIdx.x & 63;
    int node = blockIdx.x * 4 + (threadIdx.x >> 6);
    if (node >= N) return;
    float h[2];
    agg_core<2>(Hin, offsets, edges, dis, node, lane, N, Etot, b3, 1, h);
    head_mlp(h, lane, node, flag, Wp, bp, Wf1, bf1v, Wf2, bf2v, out);
}

// ---------------------------------------------------------------- MFMA GEMM tile
// 128x64 tile, BK=64, global_load_lds(16B), src-swizzled + swizzled ds_read.
// Must be called by all 256 threads of the block together (has barriers).
__device__ void gemm_tile(
    const ushort_t* __restrict__ A, const ushort_t* __restrict__ Bt,
    ushort_t* __restrict__ C, int M, int K, int Nn,
    const float* __restrict__ bias, int do_lrelu, int bx, int by) {
    __shared__ ushort_t As[128 * 64];
    __shared__ ushort_t Bs[64 * 64];

    int tid = threadIdx.x;
    int row0 = by * 128;
    int col0 = bx * 64;
    int lane = tid & 63;
    int w = tid >> 6;
    int quad = lane >> 4;
    int col = lane & 15;
    int wr = (w >> 1) * 64;
    int wc = (w & 1) * 32;

    floatx4 acc[4][2];
#pragma unroll
    for (int i = 0; i < 4; ++i)
#pragma unroll
        for (int j = 0; j < 2; ++j) acc[i][j] = (floatx4){0.f, 0.f, 0.f, 0.f};

    int aoff[4], boff[2];
#pragma unroll
    for (int rt = 0; rt < 4; ++rt) {
        int r = wr + rt * 16 + col;
        aoff[rt] = (r * 128 + quad * 16) ^ ((r & 7) << 4);
    }
#pragma unroll
    for (int ct = 0; ct < 2; ++ct) {
        int r = wc + ct * 16 + col;
        boff[ct] = (r * 128 + quad * 16) ^ ((r & 7) << 4);
    }

    for (int k0 = 0; k0 < K; k0 += 64) {
#pragma unroll
        for (int i = 0; i < 4; ++i) {
            int t = i * 256 + tid;
            int r = t >> 3;
            int g = (t & 7) ^ (r & 7);
            const ushort_t* src = A + (size_t)(row0 + r) * K + k0 + g * 8;
            GLOAD_LDS16(src, &As[t * 8]);
        }
#pragma unroll
        for (int i = 0; i < 2; ++i) {
            int t = i * 256 + tid;
            int r = t >> 3;
            int g = (t & 7) ^ (r & 7);
            const ushort_t* src = Bt + (size_t)(col0 + r) * K + k0 + g * 8;
            GLOAD_LDS16(src, &Bs[t * 8]);
        }
        __syncthreads();

#pragma unroll
        for (int ks = 0; ks < 2; ++ks) {
            short8v af[4], bf[2];
#pragma unroll
            for (int rt = 0; rt < 4; ++rt)
                af[rt] = *(const short8v*)((const char*)As + (aoff[rt] ^ (ks * 64)));
#pragma unroll
            for (int ct = 0; ct < 2; ++ct)
                bf[ct] = *(const short8v*)((const char*)Bs + (boff[ct] ^ (ks * 64)));
#pragma unroll
            for (int rt = 0; rt < 4; ++rt)
#pragma unroll
                for (int ct = 0; ct < 2; ++ct)
                    acc[rt][ct] = __builtin_amdgcn_mfma_f32_16x16x32_bf16(
                        af[rt], bf[ct], acc[rt][ct], 0, 0, 0);
        }
        __syncthreads();
    }

#pragma unroll
    for (int rt = 0; rt < 4; ++rt) {
#pragma unroll
        for (int ct = 0; ct < 2; ++ct) {
            int gcol = col0 + wc + ct * 16 + col;
            float bv = bias ? bias[gcol] : 0.f;
#pragma unroll
            for (int r = 0; r < 4; ++r) {
                int grow = row0 + wr + rt * 16 + quad * 4 + r;
                if (grow >= M) continue;
                float v = acc[rt][ct][r] + bv;
                if (do_lrelu) v = (v > 0.f) ? v : v * NEG_SLOPE;
                C[(size_t)grow * Nn + gcol] = f2us(v);
            }
        }
    }
}

__global__ __launch_bounds__(256) void mfma_gemm_kernel(
    const ushort_t* __restrict__ A, const ushort_t* __restrict__ Bt,
    ushort_t* __restrict__ C,
    int M, int K, int Nn, const float* __restrict__ bias, int do_lrelu) {
    gemm_tile(A, Bt, C, M, K, Nn, bias, do_lrelu, blockIdx.x, blockIdx.y);
}

// ---------------------------------------------------------------- fused pipeline
struct FusedParams {
    PrepDesc pd;
    const int* srcv; const int* dstv;
    int* deg; int* offsets; int* cursor; float* dis;
    int* bsumf; int* bsum2; int* gbar;
    int2* edges;
    ushort_t* xb; ushort_t* t0; ushort_t* H1; ushort_t* t2; ushort_t* H2; ushort_t* t3;
    const ushort_t* W1t; const ushort_t* W2t; const ushort_t* W3t;
    const float *b1, *b2, *b3, *Wp, *bp, *Wf1, *bf1v, *Wf2, *bf2v;
    void* out; const void* xsrc;
    int N, E, Etot;
};

__global__ __launch_bounds__(256, 4) void fused_pipeline(FusedParams P) {
    __shared__ int sbuf[256];
    const int tid = threadIdx.x;
    const int bid = blockIdx.x;
    const int nb = gridDim.x;
    const int N = P.N, E = P.E, Etot = P.Etot;
    const int lane = tid & 63, sub = tid >> 6;

    int flag = block_flag((const unsigned int*)P.xsrc);

    // ---- P0: prep (converts, transposes, x->bf16) ----
    for (int vb = bid; vb < 13 * 512; vb += nb)
        prep_task(P.pd, vb >> 9, vb & 511, tid, flag);
    gsync(&P.gbar[0], nb);

    // ---- P1: degree count ----
    for (int vb = bid; vb < (E + 255) / 256; vb += nb) {
        int i = vb * 256 + tid;
        if (i < E) {
            int d = P.dstv[i];
            d = d < 0 ? 0 : (d >= N ? N - 1 : d);
            atomicAdd(&P.deg[d], 1);
        }
    }
    gsync(&P.gbar[1], nb);

    // ---- P2a: block-local scan of (deg+1), 1024 elems / virtual block ----
    const int nsb = (N + 1023) >> 10;
    for (int vb = bid; vb < nsb; vb += nb) {
        int i0 = (vb << 10) + tid * 4;
        int d0 = (i0 + 0 < N) ? P.deg[i0 + 0] + 1 : 0;
        int d1 = (i0 + 1 < N) ? P.deg[i0 + 1] + 1 : 0;
        int d2 = (i0 + 2 < N) ? P.deg[i0 + 2] + 1 : 0;
        int d3 = (i0 + 3 < N) ? P.deg[i0 + 3] + 1 : 0;
        int s = d0 + d1 + d2 + d3;
        sbuf[tid] = s;
        __syncthreads();
        for (int off = 1; off < 256; off <<= 1) {
            int t = (tid >= off) ? sbuf[tid - off] : 0;
            __syncthreads();
            sbuf[tid] += t;
            __syncthreads();
        }
        int e = sbuf[tid] - s;   // thread-exclusive (local)
        if (i0 + 0 < N) P.offsets[i0 + 0] = e;
        e += d0;
        if (i0 + 1 < N) P.offsets[i0 + 1] = e;
        e += d1;
        if (i0 + 2 < N) P.offsets[i0 + 2] = e;
        e += d2;
        if (i0 + 3 < N) P.offsets[i0 + 3] = e;
        if (tid == 255) P.bsumf[vb] = sbuf[255];
        __syncthreads();
    }
    gsync(&P.gbar[2], nb);

    // ---- P2b: scan of block totals (block 0 only) ----
    if (bid == 0) {
        int v = (tid < nsb) ? P.bsumf[tid] : 0;
        sbuf[tid] = v;
        __syncthreads();
        for (int off = 1; off < 256; off <<= 1) {
            int t = (tid >= off) ? sbuf[tid - off] : 0;
            __syncthreads();
            sbuf[tid] += t;
            __syncthreads();
        }
        if (tid < nsb) P.bsum2[tid] = sbuf[tid] - v;
        if (tid == 255) P.offsets[N] = sbuf[255];
    }
    gsync(&P.gbar[3], nb);

    // ---- P2c: apply base; write cursor, dis ----
    for (int vb = bid; vb < nsb; vb += nb) {
        int base = P.bsum2[vb];
        int i0 = (vb << 10) + tid * 4;
#pragma unroll
        for (int j = 0; j < 4; ++j) {
            int i = i0 + j;
            if (i < N) {
                int o = P.offsets[i] + base;
                P.offsets[i] = o;
                P.cursor[i] = o;
                P.dis[i] = rsqrtf((float)(P.deg[i] + 1));
            }
        }
    }
    gsync(&P.gbar[4], nb);

    // ---- P3: fill CSR ----
    for (int vb = bid; vb < (Etot + 255) / 256; vb += nb) {
        int i = vb * 256 + tid;
        if (i < Etot) {
            int s, d;
            if (i < E) { s = P.srcv[i]; d = P.dstv[i]; }
            else { s = d = i - E; }
            s = s < 0 ? 0 : (s >= N ? N - 1 : s);
            d = d < 0 ? 0 : (d >= N ? N - 1 : d);
            int pos = atomicAdd(&P.cursor[d], 1);
            if (pos >= 0 && pos < Etot) P.edges[pos] = make_int2(s, __float_as_int(P.dis[s]));
        }
    }
    gsync(&P.gbar[5], nb);

    const int ngrp = (N + 3) / 4;
    // ---- P4: t0 = A x (VEC=2) ----
    for (int vg = bid; vg < ngrp; vg += nb) {
        int node = vg * 4 + sub;
        if (node < N) {
            float o[2];
            agg_core<2>(P.xb, P.offsets, P.edges, P.dis, node, lane, N, Etot,
                        nullptr, 0, o);
            agg_store<2>(P.t0, node, lane, o);
        }
    }
    gsync(&P.gbar[6], nb);

    const int nby = (N + 127) / 128;
    // ---- P5: H1 = lrelu(t0 W1 + b1) ----
    for (int vt = bid; vt < 8 * nby; vt += nb)
        gemm_tile(P.t0, P.W1t, P.H1, N, 128, 512, P.b1, 1, vt & 7, vt >> 3);
    gsync(&P.gbar[7], nb);

    // ---- P6: t2 = H1 W2 ----
    for (int vt = bid; vt < 4 * nby; vt += nb)
        gemm_tile(P.H1, P.W2t, P.t2, N, 512, 256, nullptr, 0, vt & 3, vt >> 2);
    gsync(&P.gbar[8], nb);

    // ---- P7: H2 = lrelu(A t2 + b2) (VEC=4) ----
    for (int vg = bid; vg < ngrp; vg += nb) {
        int node = vg * 4 + sub;
        if (node < N) {
            float o[4];
            agg_core<4>(P.t2, P.offsets, P.edges, P.dis, node, lane, N, Etot,
                        P.b2, 1, o);
            agg_store<4>(P.H2, node, lane, o);
        }
    }
    gsync(&P.gbar[9], nb);

    // ---- P8: t3 = H2 W3 ----
    for (int vt = bid; vt < 2 * nby; vt += nb)
        gemm_tile(P.H2, P.W3t, P.t3, N, 256, 128, nullptr, 0, vt & 1, vt >> 1);
    gsync(&P.gbar[10], nb);

    // ---- P9: out = head(lrelu(A t3 + b3)) ----
    for (int vg = bid; vg < ngrp; vg += nb) {
        int node = vg * 4 + sub;
        if (node < N) {
            float h[2];
            agg_core<2>(P.t3, P.offsets, P.edges, P.dis, node, lane, N, Etot,
                        P.b3, 1, h);
            head_mlp(h, lane, node, flag, P.Wp, P.bp, P.Wf1, P.bf1v, P.Wf2,
                     P.bf2v, P.out);
        }
    }
}

// ---------------------------------------------------------------- launch
extern "C" void kernel_launch(void* const* d_in, const int* in_sizes, int n_in,
                              void* d_out, int out_size, void* d_ws, size_t ws_size,
                              hipStream_t stream) {
    const int* ei = (const int*)d_in[1];

    const int N = in_sizes[0] / 128;   // 20000
    const int E = in_sizes[1] / 2;     // 320000
    const int Etot = E + N;
    const int nb = (N + 1023) / 1024;  // 20
    const int* srcv = ei;
    const int* dstv = ei + E;

    uintptr_t p = (uintptr_t)d_ws;
    auto alloc = [&](size_t bytes) -> void* {
        p = (p + 255) & ~(uintptr_t)255;
        void* r = (void*)p;
        p += bytes;
        return r;
    };
    // zero region: deg[N] | bsumf[32] | bsum2[32] | gbar[16]
    int*      deg     = (int*)alloc((size_t)(N + 80) * 4);
    int*      bsumf   = deg + N;
    int*      bsum2   = bsumf + 32;
    int*      gbar    = bsum2 + 32;
    int*      offsets = (int*)alloc((size_t)(N + 1) * 4);
    int*      cursor  = (int*)alloc((size_t)N * 4);
    float*    dis     = (float*)alloc((size_t)N * 4);
    int2*     edges   = (int2*)alloc((size_t)Etot * 8);
    ushort_t* xb      = (ushort_t*)alloc((size_t)N * 128 * 2);

    const int K1 = 128, N1 = 512, K2 = 512, N2 = 256, K3 = 256, N3 = 128;
    ushort_t* W1t = (ushort_t*)alloc((size_t)K1 * N1 * 2);
    ushort_t* W2t = (ushort_t*)alloc((size_t)K2 * N2 * 2);
    ushort_t* W3t = (ushort_t*)alloc((size_t)K3 * N3 * 2);

    float* smalls[9];
    const int wmap[9] = {4, 6, 8, 9, 10, 11, 12, 13, 14};
    for (int t = 0; t < 9; ++t)
        smalls[t] = (float*)alloc((size_t)in_sizes[wmap[t]] * 4);
    const float *b1 = smalls[0], *b2 = smalls[1], *b3 = smalls[2];
    const float *Wp = smalls[3], *bp = smalls[4];
    const float *Wf1 = smalls[5], *bf1v = smalls[6];
    const float *Wf2 = smalls[7], *bf2v = smalls[8];

    ushort_t* BufT0 = (ushort_t*)alloc((size_t)N * 128 * 2);   // t0, then t3
    ushort_t* BufH1 = (ushort_t*)alloc((size_t)N * 512 * 2);   // H1, then H2
    ushort_t* BufT2 = (ushort_t*)alloc((size_t)N * 256 * 2);   // t2
    ushort_t* t0 = BufT0;
    ushort_t* t3 = BufT0;
    ushort_t* H1 = BufH1;
    ushort_t* H2 = BufH1;
    ushort_t* t2 = BufT2;

    // zero deg + barrier counters (replaces prep zero-task; graph memset node)
    hipMemsetAsync(deg, 0, (size_t)(N + 80) * 4, stream);

    PrepDesc pd;
    for (int t = 0; t < 9; ++t) {
        pd.src[t] = d_in[wmap[t]];
        pd.dst[t] = smalls[t];
        pd.n[t] = in_sizes[wmap[t]];
        pd.K[t] = 0; pd.Nn[t] = 0;
    }
    pd.src[9]  = d_in[3]; pd.dst[9]  = W1t; pd.n[9]  = K1 * N1; pd.K[9]  = K1; pd.Nn[9]  = N1;
    pd.src[10] = d_in[5]; pd.dst[10] = W2t; pd.n[10] = K2 * N2; pd.K[10] = K2; pd.Nn[10] = N2;
    pd.src[11] = d_in[7]; pd.dst[11] = W3t; pd.n[11] = K3 * N3; pd.K[11] = K3; pd.Nn[11] = N3;
    pd.src[12] = d_in[0]; pd.dst[12] = xb;  pd.n[12] = N * 128; pd.K[12] = -2; pd.Nn[12] = 0;

    // cooperative grid size: query once, cache (co-residency guarantee)
    static int coopBlocks = -1;
    if (coopBlocks < 0) {
        int bpc = 0;
        if (hipOccupancyMaxActiveBlocksPerMultiprocessor(&bpc, fused_pipeline,
                                                         256, 0) != hipSuccess)
            bpc = 0;
        if (bpc > 8) bpc = 8;
        coopBlocks = (bpc >= 1) ? bpc * 256 : 0;
    }

    bool done = false;
    if (coopBlocks > 0) {
        FusedParams P;
        P.pd = pd;
        P.srcv = srcv; P.dstv = dstv;
        P.deg = deg; P.offsets = offsets; P.cursor = cursor; P.dis = dis;
        P.bsumf = bsumf; P.bsum2 = bsum2; P.gbar = gbar;
        P.edges = edges;
        P.xb = xb; P.t0 = t0; P.H1 = H1; P.t2 = t2; P.H2 = H2; P.t3 = t3;
        P.W1t = W1t; P.W2t = W2t; P.W3t = W3t;
        P.b1 = b1; P.b2 = b2; P.b3 = b3;
        P.Wp = Wp; P.bp = bp; P.Wf1 = Wf1; P.bf1v = bf1v;
        P.Wf2 = Wf2; P.bf2v = bf2v;
        P.out = d_out; P.xsrc = d_in[0];
        P.N = N; P.E = E; P.Etot = Etot;
        void* args[] = {(void*)&P};
        done = (hipLaunchCooperativeKernel(fused_pipeline, dim3(coopBlocks),
                                           dim3(256), args, 0u, stream) == hipSuccess);
    }

    if (!done) {
        // fallback: original multi-dispatch pipeline
        {
            dim3 g((K2 * N2 + 255) / 256, 13);
            prep_small_kernel<<<g, 256, 0, stream>>>(pd, d_in[0]);
        }
        count_deg_kernel<<<(E + 255) / 256, 256, 0, stream>>>(dstv, deg, E, N);
        scan_merged_kernel<<<nb, 1024, 0, stream>>>(deg, offsets, cursor, dis, bsumf, N);
        fill_csr_kernel<<<(Etot + 255) / 256, 256, 0, stream>>>(srcv, dstv, dis, cursor,
                                                                edges, E, N, Etot);
        int aggGrid = (N + 3) / 4;
        agg_kernel<2><<<aggGrid, 256, 0, stream>>>(xb, t0, offsets, edges, dis,
                                                   N, Etot, nullptr, 0);
        {
            dim3 g(N1 / 64, (N + 127) / 128);
            mfma_gemm_kernel<<<g, 256, 0, stream>>>(t0, W1t, H1, N, K1, N1, b1, 1);
        }
        {
            dim3 g(N2 / 64, (N + 127) / 128);
            mfma_gemm_kernel<<<g, 256, 0, stream>>>(H1, W2t, t2, N, K2, N2, nullptr, 0);
        }
        agg_kernel<4><<<aggGrid, 256, 0, stream>>>(t2, H2, offsets, edges, dis,
                                                   N, Etot, b2, 1);
        {
            dim3 g(N3 / 64, (N + 127) / 128);
            mfma_gemm_kernel<<<g, 256, 0, stream>>>(H2, W3t, t3, N, K3, N3, nullptr, 0);
        }
        agg_head_kernel<<<aggGrid, 256, 0, stream>>>(t3, offsets, edges, dis, N, Etot,
                                                     b3, Wp, bp, Wf1, bf1v, Wf2, bf2v,
                                                     d_out, d_in[0]);
    }
}

// Round 3
// 312.663 us; speedup vs baseline: 5.3973x; 5.3973x over previous
//
#include <hip/hip_runtime.h>
#include <hip/hip_bf16.h>

typedef __hip_bfloat16 bf16;
typedef unsigned short ushort_t;
typedef __attribute__((ext_vector_type(8))) short short8v;
typedef __attribute__((ext_vector_type(4))) float floatx4;

#define NEG_SLOPE 0.15f

__device__ __forceinline__ float us2f(unsigned short u) {
    unsigned int x = ((unsigned int)u) << 16;
    float f;
    __builtin_memcpy(&f, &x, 4);
    return f;
}
__device__ __forceinline__ unsigned short f2us(float v) {
    bf16 h = __float2bfloat16(v);
    unsigned short u;
    __builtin_memcpy(&u, &h, 2);
    return u;
}

// direct global->LDS async copy, 16B per lane (linear LDS dest; swizzle is
// applied on the SOURCE address + matching XOR on the ds_read side).
#define GLOAD_LDS16(gp, lp)                                                  \
    __builtin_amdgcn_global_load_lds(                                        \
        (const __attribute__((address_space(1))) unsigned int*)(gp),         \
        (__attribute__((address_space(3))) unsigned int*)(lp), 16, 0, 0)

// ---------------------------------------------------------- per-block dtype flag
// flag=1 if x is packed bf16, 0 if fp32. Votes on first 256 words of x.
// Requires blockDim.x >= 256; call before any early return.
__device__ __forceinline__ int block_flag(const unsigned int* __restrict__ xw) {
    __shared__ int cnt;
    if (threadIdx.x == 0) cnt = 0;
    __syncthreads();
    if (threadIdx.x < 256) {
        unsigned int w = xw[threadIdx.x];
        unsigned int e = (w >> 7) & 0xFF;
        if ((w & 0xFFFF) == 0 || (e >= 100 && e <= 140)) atomicAdd(&cnt, 1);
    }
    __syncthreads();
    return cnt >= 150;
}

// ---------------------------------------------------------------- prep kernel
// task types: K==0 -> fp32 convert; K>0 -> transpose W[K x Nn] -> bf16 Wt[Nn x K];
// K==-1 -> zero ints; K==-2 -> convert x to bf16 (grid-stride).
struct PrepDesc {
    const void* src[14];
    void* dst[14];
    int n[14];
    int K[14], Nn[14];
};

__global__ void prep_small_kernel(PrepDesc d, const void* __restrict__ xsrc) {
    int f = block_flag((const unsigned int*)xsrc);
    int t = blockIdx.y;
    int Kt = d.K[t];
    int nt = d.n[t];
    if (Kt == -2) {
        ushort_t* out = (ushort_t*)d.dst[t];
        const void* in = d.src[t];
        int stride = gridDim.x * blockDim.x;
        for (int i = blockIdx.x * blockDim.x + threadIdx.x; i < nt; i += stride)
            out[i] = f ? ((const unsigned short*)in)[i] : f2us(((const float*)in)[i]);
        return;
    }
    int i = blockIdx.x * blockDim.x + threadIdx.x;
    if (i >= nt) return;
    if (Kt == -1) {
        ((int*)d.dst[t])[i] = 0;
    } else if (Kt == 0) {
        ((float*)d.dst[t])[i] = f ? us2f(((const unsigned short*)d.src[t])[i])
                                  : ((const float*)d.src[t])[i];
    } else {
        int K = Kt, Nn = d.Nn[t];
        int n = i / K, k = i - n * K;
        size_t si = (size_t)k * Nn + n;
        ((ushort_t*)d.dst[t])[i] = f ? ((const unsigned short*)d.src[t])[si]
                                     : f2us(((const float*)d.src[t])[si]);
    }
}

// ---------------------------------------------------------------- CSR build
__global__ void count_deg_kernel(const int* __restrict__ dst, int* __restrict__ deg,
                                 int E, int N) {
    int i = blockIdx.x * blockDim.x + threadIdx.x;
    if (i < E) {
        int d = dst[i];
        d = d < 0 ? 0 : (d >= N ? N - 1 : d);
        atomicAdd(&deg[d], 1);
    }
}

// single-dispatch scan with decoupled lookback: block b publishes its total
// (value+1, nonzero == ready) then sums predecessors. bsumf zeroed by prep.
__global__ void scan_merged_kernel(const int* __restrict__ deg, int* __restrict__ offsets,
                                   int* __restrict__ cursor, float* __restrict__ dis,
                                   int* __restrict__ bsumf, int N) {
    __shared__ int sh[1024];
    __shared__ int base_s;
    int tid = threadIdx.x;
    int b = blockIdx.x;
    int i = b * 1024 + tid;
    int v = (i < N) ? (deg[i] + 1) : 0;
    sh[tid] = v;
    __syncthreads();
    for (int off = 1; off < 1024; off <<= 1) {
        int t = (tid >= off) ? sh[tid - off] : 0;
        __syncthreads();
        sh[tid] += t;
        __syncthreads();
    }
    if (tid == 0) {
        __hip_atomic_store(&bsumf[b], sh[1023] + 1, __ATOMIC_RELEASE,
                           __HIP_MEMORY_SCOPE_AGENT);
        int a = 0;
        for (int pb = 0; pb < b; ++pb) {
            int val;
            do {
                val = __hip_atomic_load(&bsumf[pb], __ATOMIC_ACQUIRE,
                                        __HIP_MEMORY_SCOPE_AGENT);
            } while (val == 0);
            a += val - 1;
        }
        base_s = a;
    }
    __syncthreads();
    if (i < N) {
        int base = base_s;
        int d = deg[i] + 1;
        int inc = sh[tid];
        int excl = base + inc - d;
        offsets[i] = excl;
        cursor[i] = excl;
        dis[i] = rsqrtf((float)d);
        if (i == N - 1) offsets[N] = base + inc;
    }
}

// edges[pos] = {src, bits(dis[src])}
__global__ void fill_csr_kernel(const int* __restrict__ src, const int* __restrict__ dst,
                                const float* __restrict__ dis, int* __restrict__ cursor,
                                int2* __restrict__ edges, int E, int N, int Etot) {
    int i = blockIdx.x * blockDim.x + threadIdx.x;
    int s, d;
    if (i < E) { s = src[i]; d = dst[i]; }
    else if (i < Etot) { s = d = i - E; }
    else return;
    s = s < 0 ? 0 : (s >= N ? N - 1 : s);
    d = d < 0 ? 0 : (d >= N ? N - 1 : d);
    int pos = atomicAdd(&cursor[d], 1);
    if (pos >= 0 && pos < Etot) edges[pos] = make_int2(s, __float_as_int(dis[s]));
}

// ---------------------------------------------------------------- aggregation
// 16B/lane gather: L = F/8 lanes cover one row (16B dwordx4 each), so one wave
// VMEM instruction fetches R = 64/L edges at once (F=128 -> 4, F=256 -> 2).
// 4x unroll puts 4*R edges in flight (16 for F=128), covering the average
// degree (17) in ~one latency shot. Tail is predicated (w=0), no tail loops.
// After the loop, a log2(R)-step shfl_xor butterfly merges edge-groups; every
// lane ends with the full sums for its 8-feature block (lane % L)*8.
template <int F>
__device__ __forceinline__ void agg_core16(
    const ushort_t* __restrict__ Hin, const int* __restrict__ offsets,
    const int2* __restrict__ edges, const float* __restrict__ dis,
    int node, int lane, int N, int Etot,
    const float* __restrict__ bias, int do_lrelu, float* acc /*[8]*/) {
    const int L = F / 8;           // lanes per row
    const int R = 64 / L;          // edges per wave instruction
    int g = lane / L;              // edge subgroup of this lane
    int fo = (lane % L) * 8;       // first bf16 feature this lane owns

    int beg = offsets[node], end = offsets[node + 1];
    beg = beg < 0 ? 0 : (beg > Etot ? Etot : beg);
    end = end < beg ? beg : (end > Etot ? Etot : end);

#pragma unroll
    for (int j = 0; j < 8; ++j) acc[j] = 0.f;

    for (int base = beg; base < end; base += 4 * R) {
        int2 r[4];
#pragma unroll
        for (int t = 0; t < 4; ++t) {
            int idx = base + t * R + g;
            r[t] = (idx < end) ? edges[idx] : make_int2(0, 0);  // w = 0.0f kills tail
        }
        uint4 u[4];
#pragma unroll
        for (int t = 0; t < 4; ++t) {
            int s = r[t].x;
            s = s < 0 ? 0 : (s >= N ? N - 1 : s);
            u[t] = *(const uint4*)(Hin + (size_t)s * F + fo);
        }
#pragma unroll
        for (int t = 0; t < 4; ++t) {
            float w = __int_as_float(r[t].y);
            acc[0] += w * us2f((unsigned short)(u[t].x & 0xFFFF));
            acc[1] += w * us2f((unsigned short)(u[t].x >> 16));
            acc[2] += w * us2f((unsigned short)(u[t].y & 0xFFFF));
            acc[3] += w * us2f((unsigned short)(u[t].y >> 16));
            acc[4] += w * us2f((unsigned short)(u[t].z & 0xFFFF));
            acc[5] += w * us2f((unsigned short)(u[t].z >> 16));
            acc[6] += w * us2f((unsigned short)(u[t].w & 0xFFFF));
            acc[7] += w * us2f((unsigned short)(u[t].w >> 16));
        }
    }

    // merge edge-subgroups (they differ in lane bits >= log2(L))
#pragma unroll
    for (int m = L; m < 64; m <<= 1) {
#pragma unroll
        for (int j = 0; j < 8; ++j) acc[j] += __shfl_xor(acc[j], m, 64);
    }

    float dn = dis[node];
#pragma unroll
    for (int j = 0; j < 8; ++j) {
        float a = acc[j] * dn;
        if (bias) a += bias[fo + j];
        if (do_lrelu) a = (a > 0.f) ? a : a * NEG_SLOPE;
        acc[j] = a;
    }
}

// standalone agg: lanes 0..L-1 store 16B each (one full row)
template <int F>
__global__ __launch_bounds__(256) void agg_kernel16(
    const ushort_t* __restrict__ Hin, ushort_t* __restrict__ OutB,
    const int* __restrict__ offsets, const int2* __restrict__ edges,
    const float* __restrict__ dis, int N, int Etot,
    const float* __restrict__ bias, int do_lrelu) {
    int lane = threadIdx.x & 63;
    int node = blockIdx.x * 4 + (threadIdx.x >> 6);
    if (node >= N) return;
    float a[8];
    agg_core16<F>(Hin, offsets, edges, dis, node, lane, N, Etot, bias, do_lrelu, a);
    const int L = F / 8;
    if (lane < L) {
        uint4 wv;
        wv.x = ((unsigned int)f2us(a[1]) << 16) | f2us(a[0]);
        wv.y = ((unsigned int)f2us(a[3]) << 16) | f2us(a[2]);
        wv.z = ((unsigned int)f2us(a[5]) << 16) | f2us(a[4]);
        wv.w = ((unsigned int)f2us(a[7]) << 16) | f2us(a[6]);
        *(uint4*)(OutB + (size_t)node * F + lane * 8) = wv;
    }
}

// fused agg (F=128) + head MLP. After agg_core16, lane owns feature block
// (lane&15)*8 .. +7 (replicated x4 across quads); only lanes<16 contribute to
// the 128->16 projection, then a full-wave butterfly distributes p[16].
__global__ __launch_bounds__(256) void agg_head_kernel16(
    const ushort_t* __restrict__ Hin,
    const int* __restrict__ offsets, const int2* __restrict__ edges,
    const float* __restrict__ dis, int N, int Etot,
    const float* __restrict__ b3,
    const float* __restrict__ Wp, const float* __restrict__ bp,
    const float* __restrict__ Wf1, const float* __restrict__ bf1v,
    const float* __restrict__ Wf2, const float* __restrict__ bf2v,
    void* __restrict__ out, const void* __restrict__ xsrc) {
    int flag = block_flag((const unsigned int*)xsrc);
    int lane = threadIdx.x & 63;
    int node = blockIdx.x * 4 + (threadIdx.x >> 6);
    if (node >= N) return;
    float h[8];
    agg_core16<128>(Hin, offsets, edges, dis, node, lane, N, Etot, b3, 1, h);

    float p[16];
    if (lane < 16) {
        int f0 = lane * 8;
#pragma unroll
        for (int j = 0; j < 16; ++j) {
            float s = 0.f;
#pragma unroll
            for (int k = 0; k < 8; ++k) s += h[k] * Wp[(f0 + k) * 16 + j];
            p[j] = s;
        }
    } else {
#pragma unroll
        for (int j = 0; j < 16; ++j) p[j] = 0.f;
    }
#pragma unroll
    for (int m = 1; m < 64; m <<= 1) {
#pragma unroll
        for (int j = 0; j < 16; ++j) p[j] += __shfl_xor(p[j], m, 64);
    }
    float a0 = 0.f, a1 = 0.f;
    if (lane < 32) {
        float s = bf1v[lane];
#pragma unroll
        for (int k = 0; k < 16; ++k) s += (p[k] + bp[k]) * Wf1[k * 32 + lane];
        s = (s > 0.f) ? s : s * NEG_SLOPE;
        a0 = s * Wf2[lane * 2 + 0];
        a1 = s * Wf2[lane * 2 + 1];
    }
#pragma unroll
    for (int m = 1; m < 64; m <<= 1) {
        a0 += __shfl_xor(a0, m, 64);
        a1 += __shfl_xor(a1, m, 64);
    }
    if (lane == 0) {
        float o0 = a0 + bf2v[0];
        float o1 = a1 + bf2v[1];
        if (flag) {
            unsigned int w = ((unsigned int)f2us(o1) << 16) | f2us(o0);
            *(unsigned int*)((ushort_t*)out + (size_t)node * 2) = w;
        } else {
            *(float2*)((float*)out + (size_t)node * 2) = make_float2(o0, o1);
        }
    }
}

// ---------------------------------------------------------------- MFMA GEMM
// m97-style: 128x64 tile, BK=64, global_load_lds(16B) direct staging,
// linear LDS dest + XOR-swizzled source + XOR-swizzled ds_read_b128.
// 4 waves (2x2), wave = 64x32 (4x2 tiles of 16x16x32), fp32 acc.
// A rows beyond M are loaded unguarded (gload_lds can't mask); garbage only
// feeds accumulator rows whose C-write is guarded. All A operands have live
// allocations after them in the workspace, so the <=96-row overread is safe.
__global__ __launch_bounds__(256) void mfma_gemm_kernel(
    const ushort_t* __restrict__ A, const ushort_t* __restrict__ Bt,
    ushort_t* __restrict__ C,
    int M, int K, int Nn, const float* __restrict__ bias, int do_lrelu) {
    __shared__ ushort_t As[128 * 64];   // [row][k] linear; contents src-swizzled
    __shared__ ushort_t Bs[64 * 64];

    int tid = threadIdx.x;
    int row0 = blockIdx.y * 128;
    int col0 = blockIdx.x * 64;
    int lane = tid & 63;
    int w = tid >> 6;
    int quad = lane >> 4;
    int col = lane & 15;
    int wr = (w >> 1) * 64;
    int wc = (w & 1) * 32;

    floatx4 acc[4][2];
#pragma unroll
    for (int i = 0; i < 4; ++i)
#pragma unroll
        for (int j = 0; j < 2; ++j) acc[i][j] = (floatx4){0.f, 0.f, 0.f, 0.f};

    // read-side swizzled byte offsets (row stride = 128B; granule = 16B).
    // swizzle: byte ^= (row&7)<<4  ==  granule ^= row&7.
    int aoff[4], boff[2];
#pragma unroll
    for (int rt = 0; rt < 4; ++rt) {
        int r = wr + rt * 16 + col;
        aoff[rt] = (r * 128 + quad * 16) ^ ((r & 7) << 4);
    }
#pragma unroll
    for (int ct = 0; ct < 2; ++ct) {
        int r = wc + ct * 16 + col;
        boff[ct] = (r * 128 + quad * 16) ^ ((r & 7) << 4);
    }

    for (int k0 = 0; k0 < K; k0 += 64) {
        // stage A: 128 rows x 64 ush = 16KB = 4 x (256 lanes x 16B)
#pragma unroll
        for (int i = 0; i < 4; ++i) {
            int t = i * 256 + tid;
            int r = t >> 3;                      // 8 lanes per row
            int g = (t & 7) ^ (r & 7);           // pre-swizzled source granule
            const ushort_t* src = A + (size_t)(row0 + r) * K + k0 + g * 8;
            GLOAD_LDS16(src, &As[t * 8]);
        }
        // stage B: 64 rows x 64 ush = 8KB = 2 x (256 lanes x 16B)
#pragma unroll
        for (int i = 0; i < 2; ++i) {
            int t = i * 256 + tid;
            int r = t >> 3;
            int g = (t & 7) ^ (r & 7);
            const ushort_t* src = Bt + (size_t)(col0 + r) * K + k0 + g * 8;
            GLOAD_LDS16(src, &Bs[t * 8]);
        }
        __syncthreads();   // drains vmcnt (gload_lds) + lgkm

#pragma unroll
        for (int ks = 0; ks < 2; ++ks) {
            short8v af[4], bf[2];
#pragma unroll
            for (int rt = 0; rt < 4; ++rt)
                af[rt] = *(const short8v*)((const char*)As + (aoff[rt] ^ (ks * 64)));
#pragma unroll
            for (int ct = 0; ct < 2; ++ct)
                bf[ct] = *(const short8v*)((const char*)Bs + (boff[ct] ^ (ks * 64)));
#pragma unroll
            for (int rt = 0; rt < 4; ++rt)
#pragma unroll
                for (int ct = 0; ct < 2; ++ct)
                    acc[rt][ct] = __builtin_amdgcn_mfma_f32_16x16x32_bf16(
                        af[rt], bf[ct], acc[rt][ct], 0, 0, 0);
        }
        __syncthreads();
    }

#pragma unroll
    for (int rt = 0; rt < 4; ++rt) {
#pragma unroll
        for (int ct = 0; ct < 2; ++ct) {
            int gcol = col0 + wc + ct * 16 + col;
            float bv = bias ? bias[gcol] : 0.f;
#pragma unroll
            for (int r = 0; r < 4; ++r) {
                int grow = row0 + wr + rt * 16 + quad * 4 + r;
                if (grow >= M) continue;
                float v = acc[rt][ct][r] + bv;
                if (do_lrelu) v = (v > 0.f) ? v : v * NEG_SLOPE;
                C[(size_t)grow * Nn + gcol] = f2us(v);
            }
        }
    }
}

// ---------------------------------------------------------------- launch
extern "C" void kernel_launch(void* const* d_in, const int* in_sizes, int n_in,
                              void* d_out, int out_size, void* d_ws, size_t ws_size,
                              hipStream_t stream) {
    const int* ei = (const int*)d_in[1];

    const int N = in_sizes[0] / 128;   // 20000
    const int E = in_sizes[1] / 2;     // 320000
    const int Etot = E + N;
    const int nb = (N + 1023) / 1024;  // 20
    const int* srcv = ei;
    const int* dstv = ei + E;

    uintptr_t p = (uintptr_t)d_ws;
    auto alloc = [&](size_t bytes) -> void* {
        p = (p + 255) & ~(uintptr_t)255;
        void* r = (void*)p;
        p += bytes;
        return r;
    };
    // deg + bsumf contiguous: zeroed together by prep task 12
    int*      deg     = (int*)alloc((size_t)(N + nb + 1) * 4);
    int*      bsumf   = deg + N;
    int*      offsets = (int*)alloc((size_t)(N + 1) * 4);
    int*      cursor  = (int*)alloc((size_t)N * 4);
    float*    dis     = (float*)alloc((size_t)N * 4);
    int2*     edges   = (int2*)alloc((size_t)Etot * 8);
    ushort_t* xb      = (ushort_t*)alloc((size_t)N * 128 * 2);

    const int K1 = 128, N1 = 512, K2 = 512, N2 = 256, K3 = 256, N3 = 128;
    ushort_t* W1t = (ushort_t*)alloc((size_t)K1 * N1 * 2);
    ushort_t* W2t = (ushort_t*)alloc((size_t)K2 * N2 * 2);
    ushort_t* W3t = (ushort_t*)alloc((size_t)K3 * N3 * 2);

    // small fp32 tensors: b1,b2,b3, Wp,bp, Wf1,bf1, Wf2,bf2
    float* smalls[9];
    const int wmap[9] = {4, 6, 8, 9, 10, 11, 12, 13, 14};
    for (int t = 0; t < 9; ++t)
        smalls[t] = (float*)alloc((size_t)in_sizes[wmap[t]] * 4);
    const float *b1 = smalls[0], *b2 = smalls[1], *b3 = smalls[2];
    const float *Wp = smalls[3], *bp = smalls[4];
    const float *Wf1 = smalls[5], *bf1v = smalls[6];
    const float *Wf2 = smalls[7], *bf2v = smalls[8];

    // big buffers (aliased by lifetime)
    ushort_t* BufT0 = (ushort_t*)alloc((size_t)N * 128 * 2);   // t0, then t3
    ushort_t* BufH1 = (ushort_t*)alloc((size_t)N * 512 * 2);   // H1, then H2
    ushort_t* BufT2 = (ushort_t*)alloc((size_t)N * 256 * 2);   // t2
    ushort_t* t0 = BufT0;
    ushort_t* t3 = BufT0;
    ushort_t* H1 = BufH1;
    ushort_t* H2 = BufH1;
    ushort_t* t2 = BufT2;

    // ---- prep: 9 converts, 3 transposes, zero deg+bsumf, convert x ----
    {
        PrepDesc pd;
        for (int t = 0; t < 9; ++t) {
            pd.src[t] = d_in[wmap[t]];
            pd.dst[t] = smalls[t];
            pd.n[t] = in_sizes[wmap[t]];
            pd.K[t] = 0; pd.Nn[t] = 0;
        }
        pd.src[9]  = d_in[3]; pd.dst[9]  = W1t; pd.n[9]  = K1 * N1; pd.K[9]  = K1; pd.Nn[9]  = N1;
        pd.src[10] = d_in[5]; pd.dst[10] = W2t; pd.n[10] = K2 * N2; pd.K[10] = K2; pd.Nn[10] = N2;
        pd.src[11] = d_in[7]; pd.dst[11] = W3t; pd.n[11] = K3 * N3; pd.K[11] = K3; pd.Nn[11] = N3;
        pd.src[12] = nullptr; pd.dst[12] = deg; pd.n[12] = N + nb + 1; pd.K[12] = -1; pd.Nn[12] = 0;
        pd.src[13] = d_in[0]; pd.dst[13] = xb;  pd.n[13] = N * 128;    pd.K[13] = -2; pd.Nn[13] = 0;
        dim3 g((K2 * N2 + 255) / 256, 14);
        prep_small_kernel<<<g, 256, 0, stream>>>(pd, d_in[0]);
    }

    // ---- CSR build: wide count -> lookback scan -> wide fill ----
    count_deg_kernel<<<(E + 255) / 256, 256, 0, stream>>>(dstv, deg, E, N);
    scan_merged_kernel<<<nb, 1024, 0, stream>>>(deg, offsets, cursor, dis, bsumf, N);
    fill_csr_kernel<<<(Etot + 255) / 256, 256, 0, stream>>>(srcv, dstv, dis, cursor,
                                                            edges, E, N, Etot);

    int aggGrid = (N + 3) / 4;
    // t0 = A x -> bf16 [N,128]
    agg_kernel16<128><<<aggGrid, 256, 0, stream>>>(xb, t0, offsets, edges, dis,
                                                   N, Etot, nullptr, 0);
    // H1 = lrelu(t0 W1 + b1) -> bf16 [N,512]
    {
        dim3 g(N1 / 64, (N + 127) / 128);
        mfma_gemm_kernel<<<g, 256, 0, stream>>>(t0, W1t, H1, N, K1, N1, b1, 1);
    }
    // t2 = H1 W2 -> bf16 [N,256]
    {
        dim3 g(N2 / 64, (N + 127) / 128);
        mfma_gemm_kernel<<<g, 256, 0, stream>>>(H1, W2t, t2, N, K2, N2, nullptr, 0);
    }
    // H2 = lrelu(A t2 + b2) -> bf16 [N,256]
    agg_kernel16<256><<<aggGrid, 256, 0, stream>>>(t2, H2, offsets, edges, dis,
                                                   N, Etot, b2, 1);
    // t3 = H2 W3 -> bf16 [N,128]
    {
        dim3 g(N3 / 64, (N + 127) / 128);
        mfma_gemm_kernel<<<g, 256, 0, stream>>>(H2, W3t, t3, N, K3, N3, nullptr, 0);
    }
    // H3 = lrelu(A t3 + b3) fused with head -> out
    agg_head_kernel16<<<aggGrid, 256, 0, stream>>>(t3, offsets, edges, dis, N, Etot,
                                                   b3, Wp, bp, Wf1, bf1v, Wf2, bf2v,
                                                   d_out, d_in[0]);
}

// Round 4
// 276.496 us; speedup vs baseline: 6.1033x; 1.1308x over previous
//
#include <hip/hip_runtime.h>
#include <hip/hip_bf16.h>

typedef __hip_bfloat16 bf16;
typedef unsigned short ushort_t;
typedef __attribute__((ext_vector_type(8))) short short8v;
typedef __attribute__((ext_vector_type(4))) float floatx4;

#define NEG_SLOPE 0.15f

__device__ __forceinline__ float us2f(unsigned short u) {
    unsigned int x = ((unsigned int)u) << 16;
    float f;
    __builtin_memcpy(&f, &x, 4);
    return f;
}
__device__ __forceinline__ unsigned short f2us(float v) {
    bf16 h = __float2bfloat16(v);
    unsigned short u;
    __builtin_memcpy(&u, &h, 2);
    return u;
}

// direct global->LDS async copy, 16B per lane (linear LDS dest; swizzle is
// applied on the SOURCE address + matching XOR on the ds_read side).
#define GLOAD_LDS16(gp, lp)                                                  \
    __builtin_amdgcn_global_load_lds(                                        \
        (const __attribute__((address_space(1))) unsigned int*)(gp),         \
        (__attribute__((address_space(3))) unsigned int*)(lp), 16, 0, 0)

// ---------------------------------------------------------- per-block dtype flag
// flag=1 if x is packed bf16, 0 if fp32. Votes on first 256 words of x.
// Requires blockDim.x >= 256; call before any early return.
__device__ __forceinline__ int block_flag(const unsigned int* __restrict__ xw) {
    __shared__ int cnt;
    if (threadIdx.x == 0) cnt = 0;
    __syncthreads();
    if (threadIdx.x < 256) {
        unsigned int w = xw[threadIdx.x];
        unsigned int e = (w >> 7) & 0xFF;
        if ((w & 0xFFFF) == 0 || (e >= 100 && e <= 140)) atomicAdd(&cnt, 1);
    }
    __syncthreads();
    return cnt >= 150;
}

// ---------------------------------------------------------------- prep kernel
// task types: K==0 -> fp32 convert; K>0 -> transpose W[K x Nn] -> bf16 Wt[Nn x K];
// K==-1 -> zero ints; K==-2 -> convert x to bf16 (grid-stride).
struct PrepDesc {
    const void* src[14];
    void* dst[14];
    int n[14];
    int K[14], Nn[14];
};

__global__ void prep_small_kernel(PrepDesc d, const void* __restrict__ xsrc) {
    int f = block_flag((const unsigned int*)xsrc);
    int t = blockIdx.y;
    int Kt = d.K[t];
    int nt = d.n[t];
    if (Kt == -2) {
        ushort_t* out = (ushort_t*)d.dst[t];
        const void* in = d.src[t];
        int stride = gridDim.x * blockDim.x;
        for (int i = blockIdx.x * blockDim.x + threadIdx.x; i < nt; i += stride)
            out[i] = f ? ((const unsigned short*)in)[i] : f2us(((const float*)in)[i]);
        return;
    }
    int i = blockIdx.x * blockDim.x + threadIdx.x;
    if (i >= nt) return;
    if (Kt == -1) {
        ((int*)d.dst[t])[i] = 0;
    } else if (Kt == 0) {
        ((float*)d.dst[t])[i] = f ? us2f(((const unsigned short*)d.src[t])[i])
                                  : ((const float*)d.src[t])[i];
    } else {
        int K = Kt, Nn = d.Nn[t];
        int n = i / K, k = i - n * K;
        size_t si = (size_t)k * Nn + n;
        ((ushort_t*)d.dst[t])[i] = f ? ((const unsigned short*)d.src[t])[si]
                                     : f2us(((const float*)d.src[t])[si]);
    }
}

// ---------------------------------------------------------------- CSR build
__global__ void count_deg_kernel(const int* __restrict__ dst, int* __restrict__ deg,
                                 int E, int N) {
    int i = blockIdx.x * blockDim.x + threadIdx.x;
    if (i < E) {
        int d = dst[i];
        d = d < 0 ? 0 : (d >= N ? N - 1 : d);
        atomicAdd(&deg[d], 1);
    }
}

// single-dispatch scan with decoupled lookback: block b publishes its total
// (value+1, nonzero == ready) then sums predecessors. bsumf zeroed by prep.
__global__ void scan_merged_kernel(const int* __restrict__ deg, int* __restrict__ offsets,
                                   int* __restrict__ cursor, float* __restrict__ dis,
                                   int* __restrict__ bsumf, int N) {
    __shared__ int sh[1024];
    __shared__ int base_s;
    int tid = threadIdx.x;
    int b = blockIdx.x;
    int i = b * 1024 + tid;
    int v = (i < N) ? (deg[i] + 1) : 0;
    sh[tid] = v;
    __syncthreads();
    for (int off = 1; off < 1024; off <<= 1) {
        int t = (tid >= off) ? sh[tid - off] : 0;
        __syncthreads();
        sh[tid] += t;
        __syncthreads();
    }
    if (tid == 0) {
        __hip_atomic_store(&bsumf[b], sh[1023] + 1, __ATOMIC_RELEASE,
                           __HIP_MEMORY_SCOPE_AGENT);
        int a = 0;
        for (int pb = 0; pb < b; ++pb) {
            int val;
            do {
                val = __hip_atomic_load(&bsumf[pb], __ATOMIC_ACQUIRE,
                                        __HIP_MEMORY_SCOPE_AGENT);
            } while (val == 0);
            a += val - 1;
        }
        base_s = a;
    }
    __syncthreads();
    if (i < N) {
        int base = base_s;
        int d = deg[i] + 1;
        int inc = sh[tid];
        int excl = base + inc - d;
        offsets[i] = excl;
        cursor[i] = excl;
        dis[i] = rsqrtf((float)d);
        if (i == N - 1) offsets[N] = base + inc;
    }
}

// edges[pos] = {src, bits(dis[src])}
__global__ void fill_csr_kernel(const int* __restrict__ src, const int* __restrict__ dst,
                                const float* __restrict__ dis, int* __restrict__ cursor,
                                int2* __restrict__ edges, int E, int N, int Etot) {
    int i = blockIdx.x * blockDim.x + threadIdx.x;
    int s, d;
    if (i < E) { s = src[i]; d = dst[i]; }
    else if (i < Etot) { s = d = i - E; }
    else return;
    s = s < 0 ? 0 : (s >= N ? N - 1 : s);
    d = d < 0 ? 0 : (d >= N ? N - 1 : d);
    int pos = atomicAdd(&cursor[d], 1);
    if (pos >= 0 && pos < Etot) edges[pos] = make_int2(s, __float_as_int(dis[s]));
}

// ---------------------------------------------------------------- aggregation
template <int VEC> struct LdT;
template <> struct LdT<2> { typedef unsigned int T; };
template <> struct LdT<4> { typedef uint2 T; };

template <int VEC>
__device__ __forceinline__ void addv(typename LdT<VEC>::T u, float w, float* acc);
template <>
__device__ __forceinline__ void addv<2>(unsigned int u, float w, float* acc) {
    acc[0] += w * us2f((unsigned short)(u & 0xFFFF));
    acc[1] += w * us2f((unsigned short)(u >> 16));
}
template <>
__device__ __forceinline__ void addv<4>(uint2 u, float w, float* acc) {
    acc[0] += w * us2f((unsigned short)(u.x & 0xFFFF));
    acc[1] += w * us2f((unsigned short)(u.x >> 16));
    acc[2] += w * us2f((unsigned short)(u.y & 0xFFFF));
    acc[3] += w * us2f((unsigned short)(u.y >> 16));
}

// core gather+accumulate for one node; returns post-bias, post-lrelu values.
// Latency-bound (L2/L3-resident gathers, rocprof r3: 312 GB/s, VALU 22%):
// the lever is outstanding loads. Main block is 16-deep unpredicated
// (16 broadcast edge-loads + 16 row-gathers in flight ~= one avg-degree-17
// node per latency shot), then 8/4/scalar tails.
template <int VEC>
__device__ __forceinline__ void agg_core(
    const ushort_t* __restrict__ Hin, const int* __restrict__ offsets,
    const int2* __restrict__ edges, const float* __restrict__ dis,
    int node, int lane, int N, int Etot,
    const float* __restrict__ bias, int do_lrelu, float* outv) {
    typedef typename LdT<VEC>::T LT;
    const int F = VEC * 64;
    int beg = offsets[node], end = offsets[node + 1];
    beg = beg < 0 ? 0 : (beg > Etot ? Etot : beg);
    end = end < beg ? beg : (end > Etot ? Etot : end);

    float acc[VEC];
#pragma unroll
    for (int v = 0; v < VEC; ++v) acc[v] = 0.f;

    int fo = lane * VEC;
    int e = beg;
    for (; e + 16 <= end; e += 16) {
        int2 r[16];
#pragma unroll
        for (int j = 0; j < 16; ++j) r[j] = edges[e + j];
        LT u[16];
#pragma unroll
        for (int j = 0; j < 16; ++j) {
            int s = r[j].x;
            s = s < 0 ? 0 : (s >= N ? N - 1 : s);
            u[j] = *(const LT*)(Hin + (size_t)s * F + fo);
        }
#pragma unroll
        for (int j = 0; j < 16; ++j) addv<VEC>(u[j], __int_as_float(r[j].y), acc);
    }
    if (e + 8 <= end) {
        int2 r[8];
#pragma unroll
        for (int j = 0; j < 8; ++j) r[j] = edges[e + j];
        LT u[8];
#pragma unroll
        for (int j = 0; j < 8; ++j) {
            int s = r[j].x;
            s = s < 0 ? 0 : (s >= N ? N - 1 : s);
            u[j] = *(const LT*)(Hin + (size_t)s * F + fo);
        }
#pragma unroll
        for (int j = 0; j < 8; ++j) addv<VEC>(u[j], __int_as_float(r[j].y), acc);
        e += 8;
    }
    if (e + 4 <= end) {
        int2 r[4];
#pragma unroll
        for (int j = 0; j < 4; ++j) r[j] = edges[e + j];
        LT u[4];
#pragma unroll
        for (int j = 0; j < 4; ++j) {
            int s = r[j].x;
            s = s < 0 ? 0 : (s >= N ? N - 1 : s);
            u[j] = *(const LT*)(Hin + (size_t)s * F + fo);
        }
#pragma unroll
        for (int j = 0; j < 4; ++j) addv<VEC>(u[j], __int_as_float(r[j].y), acc);
        e += 4;
    }
    for (; e < end; ++e) {
        int2 r = edges[e];
        int s = r.x;
        s = s < 0 ? 0 : (s >= N ? N - 1 : s);
        LT u = *(const LT*)(Hin + (size_t)s * F + fo);
        addv<VEC>(u, __int_as_float(r.y), acc);
    }

    float dn = dis[node];
#pragma unroll
    for (int v = 0; v < VEC; ++v) {
        float a = acc[v] * dn;
        if (bias) a += bias[fo + v];
        if (do_lrelu) a = (a > 0.f) ? a : a * NEG_SLOPE;
        outv[v] = a;
    }
}

// standalone agg: bf16 packed output
template <int VEC>
__global__ __launch_bounds__(256) void agg_kernel(
    const ushort_t* __restrict__ Hin, ushort_t* __restrict__ OutB,
    const int* __restrict__ offsets, const int2* __restrict__ edges,
    const float* __restrict__ dis, int N, int Etot,
    const float* __restrict__ bias, int do_lrelu) {
    int lane = threadIdx.x & 63;
    int node = blockIdx.x * 4 + (threadIdx.x >> 6);
    if (node >= N) return;
    float outv[VEC];
    agg_core<VEC>(Hin, offsets, edges, dis, node, lane, N, Etot, bias, do_lrelu, outv);
    size_t base = (size_t)node * (VEC * 64) + lane * VEC;
    if (VEC == 2) {
        unsigned int w = ((unsigned int)f2us(outv[1]) << 16) | f2us(outv[0]);
        *(unsigned int*)(OutB + base) = w;
    } else {
        uint2 w;
        w.x = ((unsigned int)f2us(outv[1]) << 16) | f2us(outv[0]);
        w.y = ((unsigned int)f2us(outv[3]) << 16) | f2us(outv[2]);
        *(uint2*)(OutB + base) = w;
    }
}

// fused agg (VEC=2, F=128) + head MLP: H3 stays in fp32 registers, then
// 128->16 via wave butterfly, 16->32->2 lane-parallel, lane 0 stores.
__global__ __launch_bounds__(256) void agg_head_kernel(
    const ushort_t* __restrict__ Hin,
    const int* __restrict__ offsets, const int2* __restrict__ edges,
    const float* __restrict__ dis, int N, int Etot,
    const float* __restrict__ b3,
    const float* __restrict__ Wp, const float* __restrict__ bp,
    const float* __restrict__ Wf1, const float* __restrict__ bf1v,
    const float* __restrict__ Wf2, const float* __restrict__ bf2v,
    void* __restrict__ out, const void* __restrict__ xsrc) {
    int flag = block_flag((const unsigned int*)xsrc);
    int lane = threadIdx.x & 63;
    int node = blockIdx.x * 4 + (threadIdx.x >> 6);
    if (node >= N) return;
    float h[2];
    agg_core<2>(Hin, offsets, edges, dis, node, lane, N, Etot, b3, 1, h);

    int fo = lane * 2;
    float p[16];
#pragma unroll
    for (int j = 0; j < 16; ++j)
        p[j] = h[0] * Wp[fo * 16 + j] + h[1] * Wp[(fo + 1) * 16 + j];
#pragma unroll
    for (int m = 1; m < 64; m <<= 1) {
#pragma unroll
        for (int j = 0; j < 16; ++j) p[j] += __shfl_xor(p[j], m, 64);
    }
    float a0 = 0.f, a1 = 0.f;
    if (lane < 32) {
        float s = bf1v[lane];
#pragma unroll
        for (int k = 0; k < 16; ++k) s += (p[k] + bp[k]) * Wf1[k * 32 + lane];
        s = (s > 0.f) ? s : s * NEG_SLOPE;
        a0 = s * Wf2[lane * 2 + 0];
        a1 = s * Wf2[lane * 2 + 1];
    }
#pragma unroll
    for (int m = 1; m < 64; m <<= 1) {
        a0 += __shfl_xor(a0, m, 64);
        a1 += __shfl_xor(a1, m, 64);
    }
    if (lane == 0) {
        float o0 = a0 + bf2v[0];
        float o1 = a1 + bf2v[1];
        if (flag) {
            unsigned int w = ((unsigned int)f2us(o1) << 16) | f2us(o0);
            *(unsigned int*)((ushort_t*)out + (size_t)node * 2) = w;
        } else {
            *(float2*)((float*)out + (size_t)node * 2) = make_float2(o0, o1);
        }
    }
}

// ---------------------------------------------------------------- MFMA GEMM
// m97-style: 128x64 tile, BK=64, global_load_lds(16B) direct staging,
// linear LDS dest + XOR-swizzled source + XOR-swizzled ds_read_b128.
// 4 waves (2x2), wave = 64x32 (4x2 tiles of 16x16x32), fp32 acc.
// A rows beyond M are loaded unguarded (gload_lds can't mask); garbage only
// feeds accumulator rows whose C-write is guarded. All A operands have live
// allocations after them in the workspace, so the <=96-row overread is safe.
__global__ __launch_bounds__(256) void mfma_gemm_kernel(
    const ushort_t* __restrict__ A, const ushort_t* __restrict__ Bt,
    ushort_t* __restrict__ C,
    int M, int K, int Nn, const float* __restrict__ bias, int do_lrelu) {
    __shared__ ushort_t As[128 * 64];   // [row][k] linear; contents src-swizzled
    __shared__ ushort_t Bs[64 * 64];

    int tid = threadIdx.x;
    int row0 = blockIdx.y * 128;
    int col0 = blockIdx.x * 64;
    int lane = tid & 63;
    int w = tid >> 6;
    int quad = lane >> 4;
    int col = lane & 15;
    int wr = (w >> 1) * 64;
    int wc = (w & 1) * 32;

    floatx4 acc[4][2];
#pragma unroll
    for (int i = 0; i < 4; ++i)
#pragma unroll
        for (int j = 0; j < 2; ++j) acc[i][j] = (floatx4){0.f, 0.f, 0.f, 0.f};

    // read-side swizzled byte offsets (row stride = 128B; granule = 16B).
    // swizzle: byte ^= (row&7)<<4  ==  granule ^= row&7.
    int aoff[4], boff[2];
#pragma unroll
    for (int rt = 0; rt < 4; ++rt) {
        int r = wr + rt * 16 + col;
        aoff[rt] = (r * 128 + quad * 16) ^ ((r & 7) << 4);
    }
#pragma unroll
    for (int ct = 0; ct < 2; ++ct) {
        int r = wc + ct * 16 + col;
        boff[ct] = (r * 128 + quad * 16) ^ ((r & 7) << 4);
    }

    for (int k0 = 0; k0 < K; k0 += 64) {
        // stage A: 128 rows x 64 ush = 16KB = 4 x (256 lanes x 16B)
#pragma unroll
        for (int i = 0; i < 4; ++i) {
            int t = i * 256 + tid;
            int r = t >> 3;                      // 8 lanes per row
            int g = (t & 7) ^ (r & 7);           // pre-swizzled source granule
            const ushort_t* src = A + (size_t)(row0 + r) * K + k0 + g * 8;
            GLOAD_LDS16(src, &As[t * 8]);
        }
        // stage B: 64 rows x 64 ush = 8KB = 2 x (256 lanes x 16B)
#pragma unroll
        for (int i = 0; i < 2; ++i) {
            int t = i * 256 + tid;
            int r = t >> 3;
            int g = (t & 7) ^ (r & 7);
            const ushort_t* src = Bt + (size_t)(col0 + r) * K + k0 + g * 8;
            GLOAD_LDS16(src, &Bs[t * 8]);
        }
        __syncthreads();   // drains vmcnt (gload_lds) + lgkm

#pragma unroll
        for (int ks = 0; ks < 2; ++ks) {
            short8v af[4], bf[2];
#pragma unroll
            for (int rt = 0; rt < 4; ++rt)
                af[rt] = *(const short8v*)((const char*)As + (aoff[rt] ^ (ks * 64)));
#pragma unroll
            for (int ct = 0; ct < 2; ++ct)
                bf[ct] = *(const short8v*)((const char*)Bs + (boff[ct] ^ (ks * 64)));
#pragma unroll
            for (int rt = 0; rt < 4; ++rt)
#pragma unroll
                for (int ct = 0; ct < 2; ++ct)
                    acc[rt][ct] = __builtin_amdgcn_mfma_f32_16x16x32_bf16(
                        af[rt], bf[ct], acc[rt][ct], 0, 0, 0);
        }
        __syncthreads();
    }

#pragma unroll
    for (int rt = 0; rt < 4; ++rt) {
#pragma unroll
        for (int ct = 0; ct < 2; ++ct) {
            int gcol = col0 + wc + ct * 16 + col;
            float bv = bias ? bias[gcol] : 0.f;
#pragma unroll
            for (int r = 0; r < 4; ++r) {
                int grow = row0 + wr + rt * 16 + quad * 4 + r;
                if (grow >= M) continue;
                float v = acc[rt][ct][r] + bv;
                if (do_lrelu) v = (v > 0.f) ? v : v * NEG_SLOPE;
                C[(size_t)grow * Nn + gcol] = f2us(v);
            }
        }
    }
}

// ---------------------------------------------------------------- launch
extern "C" void kernel_launch(void* const* d_in, const int* in_sizes, int n_in,
                              void* d_out, int out_size, void* d_ws, size_t ws_size,
                              hipStream_t stream) {
    const int* ei = (const int*)d_in[1];

    const int N = in_sizes[0] / 128;   // 20000
    const int E = in_sizes[1] / 2;     // 320000
    const int Etot = E + N;
    const int nb = (N + 1023) / 1024;  // 20
    const int* srcv = ei;
    const int* dstv = ei + E;

    uintptr_t p = (uintptr_t)d_ws;
    auto alloc = [&](size_t bytes) -> void* {
        p = (p + 255) & ~(uintptr_t)255;
        void* r = (void*)p;
        p += bytes;
        return r;
    };
    // deg + bsumf contiguous: zeroed together by prep task 12
    int*      deg     = (int*)alloc((size_t)(N + nb + 1) * 4);
    int*      bsumf   = deg + N;
    int*      offsets = (int*)alloc((size_t)(N + 1) * 4);
    int*      cursor  = (int*)alloc((size_t)N * 4);
    float*    dis     = (float*)alloc((size_t)N * 4);
    int2*     edges   = (int2*)alloc((size_t)Etot * 8);
    ushort_t* xb      = (ushort_t*)alloc((size_t)N * 128 * 2);

    const int K1 = 128, N1 = 512, K2 = 512, N2 = 256, K3 = 256, N3 = 128;
    ushort_t* W1t = (ushort_t*)alloc((size_t)K1 * N1 * 2);
    ushort_t* W2t = (ushort_t*)alloc((size_t)K2 * N2 * 2);
    ushort_t* W3t = (ushort_t*)alloc((size_t)K3 * N3 * 2);

    // small fp32 tensors: b1,b2,b3, Wp,bp, Wf1,bf1, Wf2,bf2
    float* smalls[9];
    const int wmap[9] = {4, 6, 8, 9, 10, 11, 12, 13, 14};
    for (int t = 0; t < 9; ++t)
        smalls[t] = (float*)alloc((size_t)in_sizes[wmap[t]] * 4);
    const float *b1 = smalls[0], *b2 = smalls[1], *b3 = smalls[2];
    const float *Wp = smalls[3], *bp = smalls[4];
    const float *Wf1 = smalls[5], *bf1v = smalls[6];
    const float *Wf2 = smalls[7], *bf2v = smalls[8];

    // big buffers (aliased by lifetime)
    ushort_t* BufT0 = (ushort_t*)alloc((size_t)N * 128 * 2);   // t0, then t3
    ushort_t* BufH1 = (ushort_t*)alloc((size_t)N * 512 * 2);   // H1, then H2
    ushort_t* BufT2 = (ushort_t*)alloc((size_t)N * 256 * 2);   // t2
    ushort_t* t0 = BufT0;
    ushort_t* t3 = BufT0;
    ushort_t* H1 = BufH1;
    ushort_t* H2 = BufH1;
    ushort_t* t2 = BufT2;

    // ---- prep: 9 converts, 3 transposes, zero deg+bsumf, convert x ----
    {
        PrepDesc pd;
        for (int t = 0; t < 9; ++t) {
            pd.src[t] = d_in[wmap[t]];
            pd.dst[t] = smalls[t];
            pd.n[t] = in_sizes[wmap[t]];
            pd.K[t] = 0; pd.Nn[t] = 0;
        }
        pd.src[9]  = d_in[3]; pd.dst[9]  = W1t; pd.n[9]  = K1 * N1; pd.K[9]  = K1; pd.Nn[9]  = N1;
        pd.src[10] = d_in[5]; pd.dst[10] = W2t; pd.n[10] = K2 * N2; pd.K[10] = K2; pd.Nn[10] = N2;
        pd.src[11] = d_in[7]; pd.dst[11] = W3t; pd.n[11] = K3 * N3; pd.K[11] = K3; pd.Nn[11] = N3;
        pd.src[12] = nullptr; pd.dst[12] = deg; pd.n[12] = N + nb + 1; pd.K[12] = -1; pd.Nn[12] = 0;
        pd.src[13] = d_in[0]; pd.dst[13] = xb;  pd.n[13] = N * 128;    pd.K[13] = -2; pd.Nn[13] = 0;
        dim3 g((K2 * N2 + 255) / 256, 14);
        prep_small_kernel<<<g, 256, 0, stream>>>(pd, d_in[0]);
    }

    // ---- CSR build: wide count -> lookback scan -> wide fill ----
    count_deg_kernel<<<(E + 255) / 256, 256, 0, stream>>>(dstv, deg, E, N);
    scan_merged_kernel<<<nb, 1024, 0, stream>>>(deg, offsets, cursor, dis, bsumf, N);
    fill_csr_kernel<<<(Etot + 255) / 256, 256, 0, stream>>>(srcv, dstv, dis, cursor,
                                                            edges, E, N, Etot);

    int aggGrid = (N + 3) / 4;
    // t0 = A x -> bf16 [N,128]
    agg_kernel<2><<<aggGrid, 256, 0, stream>>>(xb, t0, offsets, edges, dis,
                                               N, Etot, nullptr, 0);
    // H1 = lrelu(t0 W1 + b1) -> bf16 [N,512]
    {
        dim3 g(N1 / 64, (N + 127) / 128);
        mfma_gemm_kernel<<<g, 256, 0, stream>>>(t0, W1t, H1, N, K1, N1, b1, 1);
    }
    // t2 = H1 W2 -> bf16 [N,256]
    {
        dim3 g(N2 / 64, (N + 127) / 128);
        mfma_gemm_kernel<<<g, 256, 0, stream>>>(H1, W2t, t2, N, K2, N2, nullptr, 0);
    }
    // H2 = lrelu(A t2 + b2) -> bf16 [N,256]
    agg_kernel<4><<<aggGrid, 256, 0, stream>>>(t2, H2, offsets, edges, dis,
                                               N, Etot, b2, 1);
    // t3 = H2 W3 -> bf16 [N,128]
    {
        dim3 g(N3 / 64, (N + 127) / 128);
        mfma_gemm_kernel<<<g, 256, 0, stream>>>(H2, W3t, t3, N, K3, N3, nullptr, 0);
    }
    // H3 = lrelu(A t3 + b3) fused with head -> out
    agg_head_kernel<<<aggGrid, 256, 0, stream>>>(t3, offsets, edges, dis, N, Etot,
                                                 b3, Wp, bp, Wf1, bf1v, Wf2, bf2v,
                                                 d_out, d_in[0]);
}

// Round 5
// 259.156 us; speedup vs baseline: 6.5117x; 1.0669x over previous
//
#include <hip/hip_runtime.h>
#include <hip/hip_bf16.h>

typedef __hip_bfloat16 bf16;
typedef unsigned short ushort_t;
typedef __attribute__((ext_vector_type(8))) short short8v;
typedef __attribute__((ext_vector_type(4))) float floatx4;

#define NEG_SLOPE 0.15f

__device__ __forceinline__ float us2f(unsigned short u) {
    unsigned int x = ((unsigned int)u) << 16;
    float f;
    __builtin_memcpy(&f, &x, 4);
    return f;
}
__device__ __forceinline__ unsigned short f2us(float v) {
    bf16 h = __float2bfloat16(v);
    unsigned short u;
    __builtin_memcpy(&u, &h, 2);
    return u;
}

// direct global->LDS async copy, 16B per lane (linear LDS dest; swizzle is
// applied on the SOURCE address + matching XOR on the ds_read side).
#define GLOAD_LDS16(gp, lp)                                                  \
    __builtin_amdgcn_global_load_lds(                                        \
        (const __attribute__((address_space(1))) unsigned int*)(gp),         \
        (__attribute__((address_space(3))) unsigned int*)(lp), 16, 0, 0)

// ---------------------------------------------------------- per-block dtype flag
// flag=1 if x is packed bf16, 0 if fp32. Votes on first 256 words of x.
// Requires blockDim.x >= 256; call before any early return.
__device__ __forceinline__ int block_flag(const unsigned int* __restrict__ xw) {
    __shared__ int cnt;
    if (threadIdx.x == 0) cnt = 0;
    __syncthreads();
    if (threadIdx.x < 256) {
        unsigned int w = xw[threadIdx.x];
        unsigned int e = (w >> 7) & 0xFF;
        if ((w & 0xFFFF) == 0 || (e >= 100 && e <= 140)) atomicAdd(&cnt, 1);
    }
    __syncthreads();
    return cnt >= 150;
}

// ---------------------------------------------------------------- prep kernel
// task types: K==0 -> fp32 convert; K>0 -> transpose W[K x Nn] -> bf16 Wt[Nn x K];
// K==-1 -> zero ints; K==-2 -> convert x to bf16 (grid-stride).
struct PrepDesc {
    const void* src[14];
    void* dst[14];
    int n[14];
    int K[14], Nn[14];
};

__global__ void prep_small_kernel(PrepDesc d, const void* __restrict__ xsrc) {
    int f = block_flag((const unsigned int*)xsrc);
    int t = blockIdx.y;
    int Kt = d.K[t];
    int nt = d.n[t];
    if (Kt == -2) {
        ushort_t* out = (ushort_t*)d.dst[t];
        const void* in = d.src[t];
        int stride = gridDim.x * blockDim.x;
        for (int i = blockIdx.x * blockDim.x + threadIdx.x; i < nt; i += stride)
            out[i] = f ? ((const unsigned short*)in)[i] : f2us(((const float*)in)[i]);
        return;
    }
    int i = blockIdx.x * blockDim.x + threadIdx.x;
    if (i >= nt) return;
    if (Kt == -1) {
        ((int*)d.dst[t])[i] = 0;
    } else if (Kt == 0) {
        ((float*)d.dst[t])[i] = f ? us2f(((const unsigned short*)d.src[t])[i])
                                  : ((const float*)d.src[t])[i];
    } else {
        int K = Kt, Nn = d.Nn[t];
        int n = i / K, k = i - n * K;
        size_t si = (size_t)k * Nn + n;
        ((ushort_t*)d.dst[t])[i] = f ? ((const unsigned short*)d.src[t])[si]
                                     : f2us(((const float*)d.src[t])[si]);
    }
}

// ---------------------------------------------------------------- CSR build
__global__ void count_deg_kernel(const int* __restrict__ dst, int* __restrict__ deg,
                                 int E, int N) {
    int i = blockIdx.x * blockDim.x + threadIdx.x;
    if (i < E) {
        int d = dst[i];
        d = d < 0 ? 0 : (d >= N ? N - 1 : d);
        atomicAdd(&deg[d], 1);
    }
}

// single-dispatch scan with decoupled lookback: block b publishes its total
// (value+1, nonzero == ready) then sums predecessors. bsumf zeroed by prep.
__global__ void scan_merged_kernel(const int* __restrict__ deg, int* __restrict__ offsets,
                                   int* __restrict__ cursor, float* __restrict__ dis,
                                   int* __restrict__ bsumf, int N) {
    __shared__ int sh[1024];
    __shared__ int base_s;
    int tid = threadIdx.x;
    int b = blockIdx.x;
    int i = b * 1024 + tid;
    int v = (i < N) ? (deg[i] + 1) : 0;
    sh[tid] = v;
    __syncthreads();
    for (int off = 1; off < 1024; off <<= 1) {
        int t = (tid >= off) ? sh[tid - off] : 0;
        __syncthreads();
        sh[tid] += t;
        __syncthreads();
    }
    if (tid == 0) {
        __hip_atomic_store(&bsumf[b], sh[1023] + 1, __ATOMIC_RELEASE,
                           __HIP_MEMORY_SCOPE_AGENT);
        int a = 0;
        for (int pb = 0; pb < b; ++pb) {
            int val;
            do {
                val = __hip_atomic_load(&bsumf[pb], __ATOMIC_ACQUIRE,
                                        __HIP_MEMORY_SCOPE_AGENT);
            } while (val == 0);
            a += val - 1;
        }
        base_s = a;
    }
    __syncthreads();
    if (i < N) {
        int base = base_s;
        int d = deg[i] + 1;
        int inc = sh[tid];
        int excl = base + inc - d;
        offsets[i] = excl;
        cursor[i] = excl;
        dis[i] = rsqrtf((float)d);
        if (i == N - 1) offsets[N] = base + inc;
    }
}

// edges[pos] = {src, bits(dis[src])}
__global__ void fill_csr_kernel(const int* __restrict__ src, const int* __restrict__ dst,
                                const float* __restrict__ dis, int* __restrict__ cursor,
                                int2* __restrict__ edges, int E, int N, int Etot) {
    int i = blockIdx.x * blockDim.x + threadIdx.x;
    int s, d;
    if (i < E) { s = src[i]; d = dst[i]; }
    else if (i < Etot) { s = d = i - E; }
    else return;
    s = s < 0 ? 0 : (s >= N ? N - 1 : s);
    d = d < 0 ? 0 : (d >= N ? N - 1 : d);
    int pos = atomicAdd(&cursor[d], 1);
    if (pos >= 0 && pos < Etot) edges[pos] = make_int2(s, __float_as_int(dis[s]));
}

// ---------------------------------------------------------------- aggregation
template <int VEC> struct LdT;
template <> struct LdT<2> { typedef unsigned int T; };
template <> struct LdT<4> { typedef uint2 T; };

template <int VEC>
__device__ __forceinline__ void addv(typename LdT<VEC>::T u, float w, float* acc);
template <>
__device__ __forceinline__ void addv<2>(unsigned int u, float w, float* acc) {
    acc[0] += w * us2f((unsigned short)(u & 0xFFFF));
    acc[1] += w * us2f((unsigned short)(u >> 16));
}
template <>
__device__ __forceinline__ void addv<4>(uint2 u, float w, float* acc) {
    acc[0] += w * us2f((unsigned short)(u.x & 0xFFFF));
    acc[1] += w * us2f((unsigned short)(u.x >> 16));
    acc[2] += w * us2f((unsigned short)(u.y & 0xFFFF));
    acc[3] += w * us2f((unsigned short)(u.y >> 16));
}

// Process NB edges decoded from the lane-parallel edge vector `ed` via
// v_readlane (guaranteed-uniform src index & weight -> SGPRs; gathers get
// SGPR base + loop-invariant lane offset). cnt >= 0 enables scalar
// predication: edges at j0+j >= cnt contribute w = 0 (s_cselect, no exec
// mask churn). All gathers are issued before any FMA (batched latency).
template <int VEC, int NB>
__device__ __forceinline__ void edge_block(
    int2 ed, int j0, int cnt,
    const ushort_t* __restrict__ Hin, int fo, int N, float* acc) {
    typedef typename LdT<VEC>::T LT;
    const int F = VEC * 64;
    float w[NB];
    LT u[NB];
#pragma unroll
    for (int j = 0; j < NB; ++j) {
        int s = __builtin_amdgcn_readlane(ed.x, j0 + j);
        int wb = __builtin_amdgcn_readlane(ed.y, j0 + j);
        s = s < 0 ? 0 : (s >= N ? N - 1 : s);
        if (cnt >= 0 && j0 + j >= cnt) wb = 0;   // scalar predication
        w[j] = __int_as_float(wb);
        u[j] = *(const LT*)(Hin + (size_t)s * F + fo);
    }
#pragma unroll
    for (int j = 0; j < NB; ++j) addv<VEC>(u[j], w[j], acc);
}

// core gather+accumulate for one node; returns post-bias, post-lrelu values.
// r3 rocprof: aggs are latency-bound (312 GB/s HBM, VALU 22%), r4: depth
// 8->16 flat. So cut per-edge instruction cost: node is wave-uniform ->
// readfirstlane it (offsets/dis via s_load), fetch the node's edge list
// ONCE coalesced (edges[e0+lane], 1 VMEM for up to 64 edges vs 16 broadcast
// loads per 16-block), decode edges via readlane into SGPRs.
template <int VEC>
__device__ __forceinline__ void agg_core(
    const ushort_t* __restrict__ Hin, const int* __restrict__ offsets,
    const int2* __restrict__ edges, const float* __restrict__ dis,
    int node, int lane, int N, int Etot,
    const float* __restrict__ bias, int do_lrelu, float* outv) {
    const int F = VEC * 64;
    node = __builtin_amdgcn_readfirstlane(node);
    int beg = offsets[node], end = offsets[node + 1];
    beg = beg < 0 ? 0 : (beg > Etot ? Etot : beg);
    end = end < beg ? beg : (end > Etot ? Etot : end);

    float acc[VEC];
#pragma unroll
    for (int v = 0; v < VEC; ++v) acc[v] = 0.f;

    int fo = lane * VEC;

    for (int e0 = beg; e0 < end; e0 += 64) {
        int idx = e0 + lane;
        idx = idx <= Etot - 1 ? idx : Etot - 1;
        int2 ed = edges[idx];              // one coalesced load, <=64 edges
        int cnt = end - e0;
        cnt = cnt > 64 ? 64 : cnt;
        int j0 = 0;
        for (; j0 + 16 <= cnt; j0 += 16)
            edge_block<VEC, 16>(ed, j0, -1, Hin, fo, N, acc);
        if (j0 + 8 <= cnt) {
            edge_block<VEC, 8>(ed, j0, -1, Hin, fo, N, acc);
            j0 += 8;
        }
        if (j0 < cnt)
            edge_block<VEC, 8>(ed, j0, cnt, Hin, fo, N, acc);  // 1..7 valid
    }

    float dn = dis[node];
#pragma unroll
    for (int v = 0; v < VEC; ++v) {
        float a = acc[v] * dn;
        if (bias) a += bias[fo + v];
        if (do_lrelu) a = (a > 0.f) ? a : a * NEG_SLOPE;
        outv[v] = a;
    }
}

// standalone agg: bf16 packed output
template <int VEC>
__global__ __launch_bounds__(256) void agg_kernel(
    const ushort_t* __restrict__ Hin, ushort_t* __restrict__ OutB,
    const int* __restrict__ offsets, const int2* __restrict__ edges,
    const float* __restrict__ dis, int N, int Etot,
    const float* __restrict__ bias, int do_lrelu) {
    int lane = threadIdx.x & 63;
    int node = blockIdx.x * 4 + (threadIdx.x >> 6);
    if (node >= N) return;
    float outv[VEC];
    agg_core<VEC>(Hin, offsets, edges, dis, node, lane, N, Etot, bias, do_lrelu, outv);
    size_t base = (size_t)node * (VEC * 64) + lane * VEC;
    if (VEC == 2) {
        unsigned int w = ((unsigned int)f2us(outv[1]) << 16) | f2us(outv[0]);
        *(unsigned int*)(OutB + base) = w;
    } else {
        uint2 w;
        w.x = ((unsigned int)f2us(outv[1]) << 16) | f2us(outv[0]);
        w.y = ((unsigned int)f2us(outv[3]) << 16) | f2us(outv[2]);
        *(uint2*)(OutB + base) = w;
    }
}

// fused agg (VEC=2, F=128) + head MLP: H3 stays in fp32 registers, then
// 128->16 via wave butterfly, 16->32->2 lane-parallel, lane 0 stores.
__global__ __launch_bounds__(256) void agg_head_kernel(
    const ushort_t* __restrict__ Hin,
    const int* __restrict__ offsets, const int2* __restrict__ edges,
    const float* __restrict__ dis, int N, int Etot,
    const float* __restrict__ b3,
    const float* __restrict__ Wp, const float* __restrict__ bp,
    const float* __restrict__ Wf1, const float* __restrict__ bf1v,
    const float* __restrict__ Wf2, const float* __restrict__ bf2v,
    void* __restrict__ out, const void* __restrict__ xsrc) {
    int flag = block_flag((const unsigned int*)xsrc);
    int lane = threadIdx.x & 63;
    int node = blockIdx.x * 4 + (threadIdx.x >> 6);
    if (node >= N) return;
    float h[2];
    agg_core<2>(Hin, offsets, edges, dis, node, lane, N, Etot, b3, 1, h);

    int fo = lane * 2;
    float p[16];
#pragma unroll
    for (int j = 0; j < 16; ++j)
        p[j] = h[0] * Wp[fo * 16 + j] + h[1] * Wp[(fo + 1) * 16 + j];
#pragma unroll
    for (int m = 1; m < 64; m <<= 1) {
#pragma unroll
        for (int j = 0; j < 16; ++j) p[j] += __shfl_xor(p[j], m, 64);
    }
    float a0 = 0.f, a1 = 0.f;
    if (lane < 32) {
        float s = bf1v[lane];
#pragma unroll
        for (int k = 0; k < 16; ++k) s += (p[k] + bp[k]) * Wf1[k * 32 + lane];
        s = (s > 0.f) ? s : s * NEG_SLOPE;
        a0 = s * Wf2[lane * 2 + 0];
        a1 = s * Wf2[lane * 2 + 1];
    }
#pragma unroll
    for (int m = 1; m < 64; m <<= 1) {
        a0 += __shfl_xor(a0, m, 64);
        a1 += __shfl_xor(a1, m, 64);
    }
    if (lane == 0) {
        float o0 = a0 + bf2v[0];
        float o1 = a1 + bf2v[1];
        if (flag) {
            unsigned int w = ((unsigned int)f2us(o1) << 16) | f2us(o0);
            *(unsigned int*)((ushort_t*)out + (size_t)node * 2) = w;
        } else {
            *(float2*)((float*)out + (size_t)node * 2) = make_float2(o0, o1);
        }
    }
}

// ---------------------------------------------------------------- MFMA GEMM
// m97-style: 128x64 tile, BK=64, global_load_lds(16B) direct staging,
// linear LDS dest + XOR-swizzled source + XOR-swizzled ds_read_b128.
// 4 waves (2x2), wave = 64x32 (4x2 tiles of 16x16x32), fp32 acc.
// A rows beyond M are loaded unguarded (gload_lds can't mask); garbage only
// feeds accumulator rows whose C-write is guarded. All A operands have live
// allocations after them in the workspace, so the <=96-row overread is safe.
__global__ __launch_bounds__(256) void mfma_gemm_kernel(
    const ushort_t* __restrict__ A, const ushort_t* __restrict__ Bt,
    ushort_t* __restrict__ C,
    int M, int K, int Nn, const float* __restrict__ bias, int do_lrelu) {
    __shared__ ushort_t As[128 * 64];   // [row][k] linear; contents src-swizzled
    __shared__ ushort_t Bs[64 * 64];

    int tid = threadIdx.x;
    int row0 = blockIdx.y * 128;
    int col0 = blockIdx.x * 64;
    int lane = tid & 63;
    int w = tid >> 6;
    int quad = lane >> 4;
    int col = lane & 15;
    int wr = (w >> 1) * 64;
    int wc = (w & 1) * 32;

    floatx4 acc[4][2];
#pragma unroll
    for (int i = 0; i < 4; ++i)
#pragma unroll
        for (int j = 0; j < 2; ++j) acc[i][j] = (floatx4){0.f, 0.f, 0.f, 0.f};

    // read-side swizzled byte offsets (row stride = 128B; granule = 16B).
    // swizzle: byte ^= (row&7)<<4  ==  granule ^= row&7.
    int aoff[4], boff[2];
#pragma unroll
    for (int rt = 0; rt < 4; ++rt) {
        int r = wr + rt * 16 + col;
        aoff[rt] = (r * 128 + quad * 16) ^ ((r & 7) << 4);
    }
#pragma unroll
    for (int ct = 0; ct < 2; ++ct) {
        int r = wc + ct * 16 + col;
        boff[ct] = (r * 128 + quad * 16) ^ ((r & 7) << 4);
    }

    for (int k0 = 0; k0 < K; k0 += 64) {
        // stage A: 128 rows x 64 ush = 16KB = 4 x (256 lanes x 16B)
#pragma unroll
        for (int i = 0; i < 4; ++i) {
            int t = i * 256 + tid;
            int r = t >> 3;                      // 8 lanes per row
            int g = (t & 7) ^ (r & 7);           // pre-swizzled source granule
            const ushort_t* src = A + (size_t)(row0 + r) * K + k0 + g * 8;
            GLOAD_LDS16(src, &As[t * 8]);
        }
        // stage B: 64 rows x 64 ush = 8KB = 2 x (256 lanes x 16B)
#pragma unroll
        for (int i = 0; i < 2; ++i) {
            int t = i * 256 + tid;
            int r = t >> 3;
            int g = (t & 7) ^ (r & 7);
            const ushort_t* src = Bt + (size_t)(col0 + r) * K + k0 + g * 8;
            GLOAD_LDS16(src, &Bs[t * 8]);
        }
        __syncthreads();   // drains vmcnt (gload_lds) + lgkm

#pragma unroll
        for (int ks = 0; ks < 2; ++ks) {
            short8v af[4], bf[2];
#pragma unroll
            for (int rt = 0; rt < 4; ++rt)
                af[rt] = *(const short8v*)((const char*)As + (aoff[rt] ^ (ks * 64)));
#pragma unroll
            for (int ct = 0; ct < 2; ++ct)
                bf[ct] = *(const short8v*)((const char*)Bs + (boff[ct] ^ (ks * 64)));
#pragma unroll
            for (int rt = 0; rt < 4; ++rt)
#pragma unroll
                for (int ct = 0; ct < 2; ++ct)
                    acc[rt][ct] = __builtin_amdgcn_mfma_f32_16x16x32_bf16(
                        af[rt], bf[ct], acc[rt][ct], 0, 0, 0);
        }
        __syncthreads();
    }

#pragma unroll
    for (int rt = 0; rt < 4; ++rt) {
#pragma unroll
        for (int ct = 0; ct < 2; ++ct) {
            int gcol = col0 + wc + ct * 16 + col;
            float bv = bias ? bias[gcol] : 0.f;
#pragma unroll
            for (int r = 0; r < 4; ++r) {
                int grow = row0 + wr + rt * 16 + quad * 4 + r;
                if (grow >= M) continue;
                float v = acc[rt][ct][r] + bv;
                if (do_lrelu) v = (v > 0.f) ? v : v * NEG_SLOPE;
                C[(size_t)grow * Nn + gcol] = f2us(v);
            }
        }
    }
}

// ---------------------------------------------------------------- launch
extern "C" void kernel_launch(void* const* d_in, const int* in_sizes, int n_in,
                              void* d_out, int out_size, void* d_ws, size_t ws_size,
                              hipStream_t stream) {
    const int* ei = (const int*)d_in[1];

    const int N = in_sizes[0] / 128;   // 20000
    const int E = in_sizes[1] / 2;     // 320000
    const int Etot = E + N;
    const int nb = (N + 1023) / 1024;  // 20
    const int* srcv = ei;
    const int* dstv = ei + E;

    uintptr_t p = (uintptr_t)d_ws;
    auto alloc = [&](size_t bytes) -> void* {
        p = (p + 255) & ~(uintptr_t)255;
        void* r = (void*)p;
        p += bytes;
        return r;
    };
    // deg + bsumf contiguous: zeroed together by prep task 12
    int*      deg     = (int*)alloc((size_t)(N + nb + 1) * 4);
    int*      bsumf   = deg + N;
    int*      offsets = (int*)alloc((size_t)(N + 1) * 4);
    int*      cursor  = (int*)alloc((size_t)N * 4);
    float*    dis     = (float*)alloc((size_t)N * 4);
    int2*     edges   = (int2*)alloc((size_t)Etot * 8);
    ushort_t* xb      = (ushort_t*)alloc((size_t)N * 128 * 2);

    const int K1 = 128, N1 = 512, K2 = 512, N2 = 256, K3 = 256, N3 = 128;
    ushort_t* W1t = (ushort_t*)alloc((size_t)K1 * N1 * 2);
    ushort_t* W2t = (ushort_t*)alloc((size_t)K2 * N2 * 2);
    ushort_t* W3t = (ushort_t*)alloc((size_t)K3 * N3 * 2);

    // small fp32 tensors: b1,b2,b3, Wp,bp, Wf1,bf1, Wf2,bf2
    float* smalls[9];
    const int wmap[9] = {4, 6, 8, 9, 10, 11, 12, 13, 14};
    for (int t = 0; t < 9; ++t)
        smalls[t] = (float*)alloc((size_t)in_sizes[wmap[t]] * 4);
    const float *b1 = smalls[0], *b2 = smalls[1], *b3 = smalls[2];
    const float *Wp = smalls[3], *bp = smalls[4];
    const float *Wf1 = smalls[5], *bf1v = smalls[6];
    const float *Wf2 = smalls[7], *bf2v = smalls[8];

    // big buffers (aliased by lifetime)
    ushort_t* BufT0 = (ushort_t*)alloc((size_t)N * 128 * 2);   // t0, then t3
    ushort_t* BufH1 = (ushort_t*)alloc((size_t)N * 512 * 2);   // H1, then H2
    ushort_t* BufT2 = (ushort_t*)alloc((size_t)N * 256 * 2);   // t2
    ushort_t* t0 = BufT0;
    ushort_t* t3 = BufT0;
    ushort_t* H1 = BufH1;
    ushort_t* H2 = BufH1;
    ushort_t* t2 = BufT2;

    // ---- prep: 9 converts, 3 transposes, zero deg+bsumf, convert x ----
    {
        PrepDesc pd;
        for (int t = 0; t < 9; ++t) {
            pd.src[t] = d_in[wmap[t]];
            pd.dst[t] = smalls[t];
            pd.n[t] = in_sizes[wmap[t]];
            pd.K[t] = 0; pd.Nn[t] = 0;
        }
        pd.src[9]  = d_in[3]; pd.dst[9]  = W1t; pd.n[9]  = K1 * N1; pd.K[9]  = K1; pd.Nn[9]  = N1;
        pd.src[10] = d_in[5]; pd.dst[10] = W2t; pd.n[10] = K2 * N2; pd.K[10] = K2; pd.Nn[10] = N2;
        pd.src[11] = d_in[7]; pd.dst[11] = W3t; pd.n[11] = K3 * N3; pd.K[11] = K3; pd.Nn[11] = N3;
        pd.src[12] = nullptr; pd.dst[12] = deg; pd.n[12] = N + nb + 1; pd.K[12] = -1; pd.Nn[12] = 0;
        pd.src[13] = d_in[0]; pd.dst[13] = xb;  pd.n[13] = N * 128;    pd.K[13] = -2; pd.Nn[13] = 0;
        dim3 g((K2 * N2 + 255) / 256, 14);
        prep_small_kernel<<<g, 256, 0, stream>>>(pd, d_in[0]);
    }

    // ---- CSR build: wide count -> lookback scan -> wide fill ----
    count_deg_kernel<<<(E + 255) / 256, 256, 0, stream>>>(dstv, deg, E, N);
    scan_merged_kernel<<<nb, 1024, 0, stream>>>(deg, offsets, cursor, dis, bsumf, N);
    fill_csr_kernel<<<(Etot + 255) / 256, 256, 0, stream>>>(srcv, dstv, dis, cursor,
                                                            edges, E, N, Etot);

    int aggGrid = (N + 3) / 4;
    // t0 = A x -> bf16 [N,128]
    agg_kernel<2><<<aggGrid, 256, 0, stream>>>(xb, t0, offsets, edges, dis,
                                               N, Etot, nullptr, 0);
    // H1 = lrelu(t0 W1 + b1) -> bf16 [N,512]
    {
        dim3 g(N1 / 64, (N + 127) / 128);
        mfma_gemm_kernel<<<g, 256, 0, stream>>>(t0, W1t, H1, N, K1, N1, b1, 1);
    }
    // t2 = H1 W2 -> bf16 [N,256]
    {
        dim3 g(N2 / 64, (N + 127) / 128);
        mfma_gemm_kernel<<<g, 256, 0, stream>>>(H1, W2t, t2, N, K2, N2, nullptr, 0);
    }
    // H2 = lrelu(A t2 + b2) -> bf16 [N,256]
    agg_kernel<4><<<aggGrid, 256, 0, stream>>>(t2, H2, offsets, edges, dis,
                                               N, Etot, b2, 1);
    // t3 = H2 W3 -> bf16 [N,128]
    {
        dim3 g(N3 / 64, (N + 127) / 128);
        mfma_gemm_kernel<<<g, 256, 0, stream>>>(H2, W3t, t3, N, K3, N3, nullptr, 0);
    }
    // H3 = lrelu(A t3 + b3) fused with head -> out
    agg_head_kernel<<<aggGrid, 256, 0, stream>>>(t3, offsets, edges, dis, N, Etot,
                                                 b3, Wp, bp, Wf1, bf1v, Wf2, bf2v,
                                                 d_out, d_in[0]);
}